// Round 15
// baseline (449.524 us; speedup 1.0000x reference)
//
#include <hip/hip_runtime.h>
#include <hip/hip_bf16.h>
#include <cstdint>

// ---------------------------------------------------------------------------
// DGCNN forward on MI355X. Math f32; conv1d via bf16 MFMA on packed
// fragment layouts; kNN via FUSED dist+topk.
// R28: raise fused-tg occupancy. R27 evidence: removing ALL bank conflicts
// (4.23M->0) left tg at 85.5us, VALUBusy 35%, occ 20% -> latency-bound and
// GRID-limited (512 fused blocks / 256 CUs = 2 blocks/CU; LDS 36.6KB would
// allow 4). Now 1024 fused blocks x 8 rows (2 rows/wave, acc[2][16]): LDS
// per block unchanged -> 4 blocks/CU co-resident, VGPR ~92->~65. Per-row
// staging +25% (16 ops vs ~420 compute per c0) -- cheap vs 2x latency
// hiding. Bit-identical D per (row,col) (FMA order unchanged) -> absmax
// canary 0.02050781. Kept: conflict-free col ownership {lane+64j}, banked
// stats atomics + 8-bank bn sum, edge XCD batch affinity, convert
// compaction + raw MLP reads, c1pool single-pass, stage-4 hout skip.
// ---------------------------------------------------------------------------

static constexpr int BB  = 8;
static constexpr int NN  = 1024;
static constexpr int KNB = 20;
static constexpr float BNEPS = 1e-5f;

static constexpr int NIN = 25;

__constant__ int c_cum[NIN + 1] = {
    0, 24576, 24960, 33152, 49536, 115072, 639360,
    1687936, 1819008, 1819264, 1829504, 1829544, 1829608, 1829672, 1829736,
    1829800, 1829928, 1830056, 1830312, 1830568, 1831592, 1832616, 1833128,
    1833640, 1833896, 1834152};
__constant__ int c_trO[NIN] = {0, 64, 64, 128, 256, 1024, 0, 0, 0, 0, 0,
                               0, 0, 0, 0, 0, 0, 0, 0, 0, 0, 0, 0, 0, 0};
__constant__ int c_trI[NIN] = {0, 6, 128, 128, 256, 512, 0, 0, 0, 0, 0,
                               0, 0, 0, 0, 0, 0, 0, 0, 0, 0, 0, 0, 0, 0};

enum : int {
  XIN = 0, WT1 = 24576, WT2 = 24960, WT3 = 33152, WT4 = 49536, WT5 = 115072,
  WL1 = 639360, WL2 = 1687936, BL2o = 1819008, WL3 = 1819264, BL3o = 1829504,
  G1 = 1829544, B1o = 1829608, G2 = 1829672, B2o = 1829736,
  G3 = 1829800, B3o = 1829928, G4 = 1830056, B4o = 1830312,
  G5 = 1830568, B5o = 1831592, G6 = 1832616, B6o = 1833128,
  G7 = 1833640, B7o = 1833896,
  IDXo = 1842432,       // 163840 i32
  HCATo = 2006272,      // 8*512*1024 f
  STATSo = 6200576,     // 5 layers * 4096 f (stages 0-3: 8-banked partials)
  Z2048o = 6237440,     // 8*2048 f
  Z1o = 6253824,        // 8*512 f
  Z2o = 6257920,        // 8*256 f
  FLAGSo = 6259968,     // 32 i32
  DISTo = 6260736,      // window (U/Vd/ysel; D not materialized)
  HBFo  = 14649344,     // packed bf16 h: 8*1024*512 shorts (2M float slots)
  W5BFo = 16746496      // packed bf16 w5: 512K shorts -> ends 17008640
};
static constexpr int TOTAL_IN = 1834152;
static constexpr int NCONV = (TOTAL_IN + 255) / 256;   // full-copy blocks (!mf)
static constexpr int NMAIN_ELEMS = 115072 + 4608;      // 119680
static constexpr int NMAIN_MF = (NMAIN_ELEMS + 255) / 256;  // 468 blocks
static constexpr int U_OFF   = DISTo + 0;
static constexpr int VD_OFF  = DISTo + 2097152;
static constexpr int YS_OFF  = DISTo + 4194304;
static constexpr int Y5_OFF  = DISTo + 0;
static constexpr size_t WS_NEED_MFMA = (size_t)17008640 * 4;  // ~68 MB

struct Ptrs { const void* p[NIN]; };

typedef short short8v __attribute__((ext_vector_type(8)));
typedef float f32x16 __attribute__((ext_vector_type(16)));

__device__ __forceinline__ float lrelu(float y) { return (y < 0.f) ? 0.2f * y : y; }
__device__ __forceinline__ unsigned short f2b(float f) {
  unsigned u = __float_as_uint(f);
  unsigned r = (u + 0x7FFFu + ((u >> 16) & 1u)) >> 16;   // RNE
  return (unsigned short)r;
}
// sortable key: monotone map float -> u32 (larger float -> larger key)
__device__ __forceinline__ unsigned f2s(float f) {
  const unsigned s = __float_as_uint(f);
  return s ^ ((unsigned)((int)s >> 31) | 0x80000000u);
}
__device__ __forceinline__ float load_in(const void* p, int fl, int idx) {
  if (fl == 2) return 0.f;
  if (fl == 1) {
    const unsigned short u = ((const unsigned short*)p)[idx];
    return __uint_as_float(((unsigned)u) << 16);
  }
  return ((const float*)p)[idx];
}
__device__ __forceinline__ int mbcnt64(unsigned long long m) {
  return __builtin_amdgcn_mbcnt_hi((unsigned)(m >> 32),
                                   __builtin_amdgcn_mbcnt_lo((unsigned)m, 0));
}

// ---------------------------------------------------------------------------
// dtype detection
// ---------------------------------------------------------------------------
__global__ void detect_kernel(Ptrs ptrs, int* __restrict__ flags) {
  const int i = blockIdx.x;
  const unsigned* p = (const unsigned*)ptrs.p[i];
  const int n = c_cum[i + 1] - c_cum[i];
  int words = n >> 1; if (words > 64) words = 64;
  const int t = threadIdx.x;
  unsigned w = (t < words) ? p[t] : 0u;
  bool nz = (w != 0u);
  unsigned e = (w >> 7) & 0xFFu;
  bool pl = nz && (e >= 96u) && (e <= 140u);
  unsigned long long mnz = __ballot(nz);
  unsigned long long mpl = __ballot(pl);
  if (t == 0) {
    int cnz = __popcll(mnz), cpl = __popcll(mpl);
    flags[i] = (cnz == 0) ? 2 : ((2 * cpl > words) ? 1 : 0);
  }
}

// ---------------------------------------------------------------------------
// convert: main blocks convert+transpose inputs; tail1 zeroes stats;
// tail2 packs w5 (raw input -> MFMA A-fragment bf16) if do_w5.
// ---------------------------------------------------------------------------
__global__ void convert_kernel(Ptrs ptrs, const int* __restrict__ flags,
                               float* __restrict__ ws, int do_w5, int nmain) {
  const int bx = blockIdx.x;
  const int t = threadIdx.x;
  if (bx >= nmain + 80) {            // tail2: w5 packing
    if (!do_w5) return;
    const int g = (bx - nmain - 80) * 256 + t;   // 0..65535
    const int lane = g & 63;
    const int kb = (g >> 6) & 31;
    const int ot = g >> 11;
    const int o = ot * 32 + (lane & 31);
    const int k0 = kb * 16 + (lane >> 5) * 8;
    const void* w5raw = ptrs.p[5];
    const int fl = flags[5];
    unsigned u[4];
#pragma unroll
    for (int h = 0; h < 4; ++h) {
      const unsigned short lo = f2b(load_in(w5raw, fl, o * 512 + k0 + 2 * h));
      const unsigned short hi = f2b(load_in(w5raw, fl, o * 512 + k0 + 2 * h + 1));
      u[h] = (unsigned)lo | ((unsigned)hi << 16);
    }
    unsigned short* w5p = (unsigned short*)(ws + W5BFo);
    *(uint4*)&w5p[(size_t)g * 8] = make_uint4(u[0], u[1], u[2], u[3]);
    return;
  }
  if (bx >= nmain) {                 // tail1: zero stats
    const int z = (bx - nmain) * 256 + t;
    if (z < 20480) ws[STATSo + z] = 0.f;
    return;
  }
  int e;
  if (do_w5) {                       // compact map
    const int e2 = bx * 256 + t;
    if (e2 >= NMAIN_ELEMS) return;
    e = (e2 < 115072) ? e2 : (e2 - 115072 + 1829544);
  } else {
    e = bx * 256 + t;
    if (e >= TOTAL_IN) return;
  }
  int i = 0;
  while (e >= c_cum[i + 1]) ++i;
  const int el = e - c_cum[i];
  int src;
  const int O = c_trO[i];
  if (O > 0) {
    const int I = c_trI[i];
    const int o = el % O, ii = el / O;
    src = o * I + ii;
  } else src = el;
  ws[e] = load_in(ptrs.p[i], flags[i], src);
}

// ---------------------------------------------------------------------------
// merged FUSED dist+topk (blocks 0..1023) + gemm_uv (blocks 1024..).
// Fused block = (batch bx&7, row-group bx>>3): 8 rows x 1024 cols, 2
// rows/wave. Lane owns cols {lane+64j}: LDS bank = lane%32 -> free.
// ---------------------------------------------------------------------------
template <int C, int O>
__global__ __launch_bounds__(256) void tg_kernel(
    const float* __restrict__ xbase, int bstr, const float* __restrict__ WT,
    float* __restrict__ U, float* __restrict__ Vd, int* __restrict__ idxb) {
  constexpr int OT = O / 64;
  __shared__ __align__(16) float s_mem[8 * 1024 + 64 + 1024];
  const int t = threadIdx.x;
  if (blockIdx.x < 1024) {
    float (*s_b)[1024] = (float(*)[1024])s_mem;
    float (*s_a)[8] = (float(*)[8])(s_mem + 8192);
    float* s_xx = s_mem + 8192 + 64;
    const int b = blockIdx.x & 7;          // batch (XCD-affine)
    const int rg = blockIdx.x >> 3;        // 0..127
    const int r0 = rg * 8;
    const float* xb = xbase + (size_t)b * bstr;
    const int wv = t >> 6, lane = t & 63;
    float acc[2][16] = {};
    float xxa[4] = {0.f, 0.f, 0.f, 0.f};
    for (int c0 = 0; c0 < C; c0 += 8) {
      const int kc = (C - c0 < 8) ? (C - c0) : 8;
      __syncthreads();
      for (int i = t; i < 2048; i += 256) {          // B: [8][1024] (zero-pad)
        const int cc = i >> 8, col4 = (i & 255) * 4;
        float4 v = make_float4(0.f, 0.f, 0.f, 0.f);
        if (cc < kc) v = *(const float4*)&xb[(c0 + cc) * NN + col4];
        *(float4*)&s_b[cc][col4] = v;
      }
      if (t < 64) {                                   // A: [8][8]
        const int rr = t >> 3, cc = t & 7;
        s_a[rr][cc] = (cc < kc) ? xb[(c0 + cc) * NN + r0 + rr] : 0.f;
      }
      __syncthreads();
#pragma unroll
      for (int cc = 0; cc < 8; ++cc) {
        float a2[2];
#pragma unroll
        for (int ri = 0; ri < 2; ++ri) a2[ri] = s_a[wv * 2 + ri][cc];
        float bv[16];
#pragma unroll
        for (int j = 0; j < 16; ++j) bv[j] = s_b[cc][lane + 64 * j];
#pragma unroll
        for (int ri = 0; ri < 2; ++ri)
#pragma unroll
          for (int j = 0; j < 16; ++j)
            acc[ri][j] = fmaf(a2[ri], bv[j], acc[ri][j]);
#pragma unroll
        for (int q = 0; q < 4; ++q) {                // col-norm partials
          const float v = s_b[cc][q * 256 + t];
          xxa[q] = fmaf(v, v, xxa[q]);
        }
      }
    }
    __syncthreads();
#pragma unroll
    for (int q = 0; q < 4; ++q) s_xx[q * 256 + t] = xxa[q];
    __syncthreads();
    float xm[16];
#pragma unroll
    for (int j = 0; j < 16; ++j) xm[j] = s_xx[lane + 64 * j];
    unsigned long long* scw = (unsigned long long*)s_mem + wv * 128;
#pragma unroll
    for (int ri = 0; ri < 2; ++ri) {     // UNROLLED: acc indices static (rule #20)
      const int rloc = r0 + wv * 2 + ri;
      const int rowg = (b << 10) + rloc;
      const float xxn = s_xx[rloc];
      unsigned k16[16];
      unsigned lmax = 0u;
#pragma unroll
      for (int j = 0; j < 16; ++j) {
        k16[j] = f2s(2.f * acc[ri][j] - xxn - xm[j]);
        lmax = (k16[j] > lmax) ? k16[j] : lmax;
      }
      // binary search: largest T with #lanes(lmax >= T) >= 20
      unsigned T = 0u;
      for (int bb2 = 31; bb2 >= 0; --bb2) {
        const unsigned cand = T | (1u << bb2);
        if (__popcll(__ballot(lmax >= cand)) >= KNB) T = cand;
      }
      int cnt = 0;
#pragma unroll
      for (int j = 0; j < 16; ++j) cnt += (k16[j] >= T) ? 1 : 0;
      int n_c = 0, off = 0;
#pragma unroll
      for (int bb2 = 0; bb2 < 5; ++bb2) {
        const unsigned long long m = __ballot((cnt >> bb2) & 1);
        n_c += __popcll(m) << bb2;
        off += mbcnt64(m) << bb2;
      }
      if (n_c <= 128) {
#pragma unroll
        for (int j = 0; j < 16; ++j)
          if (k16[j] >= T) {
            const int ci = lane + 64 * j;
            scw[off] = (((unsigned long long)k16[j]) << 32) |
                       (unsigned long long)(0xFFFFFFFFu ^ (unsigned)ci);
            ++off;
          }
        if (n_c <= 64) {
          unsigned long long mye = 0ULL;
          if (lane < n_c) mye = scw[lane];
          int rank = 0;
          for (int j = 0; j < n_c; ++j) {
            const unsigned eh =
                (unsigned)__builtin_amdgcn_readlane((int)(mye >> 32), j);
            const unsigned el =
                (unsigned)__builtin_amdgcn_readlane((int)(mye & 0xFFFFFFFFu), j);
            const unsigned long long ej = (((unsigned long long)eh) << 32) | el;
            rank += (ej > mye) ? 1 : 0;
          }
          if (lane < n_c && rank < KNB)
            idxb[rowg * KNB + rank] =
                (int)(0xFFFFFFFFu ^ (unsigned)(mye & 0xFFFFFFFFu));
        } else {
          const unsigned long long mye = (lane < n_c) ? scw[lane] : 0ULL;
          const unsigned long long mye2 =
              (64 + lane < n_c) ? scw[64 + lane] : 0ULL;
          int r1 = 0, r2 = 0;
          for (int j = 0; j < n_c; ++j) {
            const unsigned long long ej = scw[j];   // broadcast read
            r1 += (ej > mye) ? 1 : 0;
            r2 += (ej > mye2) ? 1 : 0;
          }
          if (lane < n_c && r1 < KNB)
            idxb[rowg * KNB + r1] = (int)(0xFFFFFFFFu ^ (unsigned)mye);
          if (64 + lane < n_c && r2 < KNB)
            idxb[rowg * KNB + r2] = (int)(0xFFFFFFFFu ^ (unsigned)mye2);
        }
      } else {
        // ---- composite-u64 extraction fallback (exact; ~never) ----
        unsigned long long q[4] = {0ULL, 0ULL, 0ULL, 0ULL};
        unsigned emit = 0;
#pragma unroll
        for (int j = 0; j < 16; ++j) {
          const int ci = lane + 64 * j;
          const unsigned long long c =
              (((unsigned long long)k16[j]) << 32) |
              (unsigned long long)(0xFFFFFFFFu ^ (unsigned)ci);
          if (c > q[3]) {
            q[3] = c;
            if (q[3] > q[2]) { auto tv = q[2]; q[2] = q[3]; q[3] = tv; }
            if (q[2] > q[1]) { auto tv = q[1]; q[1] = q[2]; q[2] = tv; }
            if (q[1] > q[0]) { auto tv = q[0]; q[0] = q[1]; q[1] = tv; }
          }
        }
        for (int kk = 0; kk < KNB; ++kk) {
          unsigned long long best = q[0];
          for (int o2 = 1; o2 < 64; o2 <<= 1) {
            const unsigned long long p =
                (unsigned long long)__shfl_xor((long long)best, o2, 64);
            best = (p > best) ? p : best;
          }
          if (lane == 0)
            idxb[rowg * KNB + kk] = (int)(0xFFFFFFFFu ^ (unsigned)best);
          if (q[0] == best) {           // unique owner (idx in composite)
            const int ci = (int)(0xFFFFFFFFu ^ (unsigned)best);
            const int j = (ci - lane) >> 6;
            emit |= 1u << j;
            q[0] = q[1]; q[1] = q[2]; q[2] = q[3]; q[3] = 0ULL;
            if (q[0] == 0ULL && __popc(emit) < 16) {
              for (int j2 = 0; j2 < 16; ++j2)
                if (!((emit >> j2) & 1u)) {
                  const int ci2 = lane + 64 * j2;
                  const unsigned long long c2 =
                      (((unsigned long long)k16[j2]) << 32) |
                      (unsigned long long)(0xFFFFFFFFu ^ (unsigned)ci2);
                  if (c2 > q[3]) {
                    q[3] = c2;
                    if (q[3] > q[2]) { auto tv = q[2]; q[2] = q[3]; q[3] = tv; }
                    if (q[2] > q[1]) { auto tv = q[1]; q[1] = q[2]; q[2] = tv; }
                    if (q[1] > q[0]) { auto tv = q[0]; q[0] = q[1]; q[1] = tv; }
                  }
                }
            }
          }
        }
      }
    }
    return;
  }
  // ---- gemm_uv part (LDS aliased onto s_mem) ----
  float (*s_x)[64] = (float(*)[64])(s_mem);
  float (*s_wn)[64] = (float(*)[64])(s_mem + 512);
  float (*s_wc)[64] = (float(*)[64])(s_mem + 1024);
  const int bx = blockIdx.x - 1024;
  const int b = bx / (16 * OT);
  const int r = bx % (16 * OT);
  const int n0 = (r / OT) * 64;
  const int o0 = (r % OT) * 64;
  const float* xb = xbase + (size_t)b * bstr;
  const int tn = (t >> 4) * 4;
  const int to = (t & 15) * 4;
  float accU[4][4] = {}, accC[4][4] = {};
  for (int c0 = 0; c0 < C; c0 += 8) {
    const int kc = (C - c0 < 8) ? (C - c0) : 8;
    for (int i = t; i < 8 * 64; i += 256) {
      const int cc = i >> 6, col = i & 63;
      const bool ok = cc < kc;
      s_x[cc][col]  = ok ? xb[(c0 + cc) * NN + n0 + col] : 0.f;
      s_wn[cc][col] = ok ? WT[(c0 + cc) * O + o0 + col] : 0.f;
      s_wc[cc][col] = ok ? WT[(C + c0 + cc) * O + o0 + col] : 0.f;
    }
    __syncthreads();
#pragma unroll
    for (int cc = 0; cc < 8; ++cc) {
      const float4 xv = *(const float4*)&s_x[cc][tn];
      const float4 wn = *(const float4*)&s_wn[cc][to];
      const float4 wc = *(const float4*)&s_wc[cc][to];
      const float xa[4] = {xv.x, xv.y, xv.z, xv.w};
      const float na[4] = {wn.x, wn.y, wn.z, wn.w};
      const float ca[4] = {wc.x, wc.y, wc.z, wc.w};
#pragma unroll
      for (int i = 0; i < 4; ++i)
#pragma unroll
        for (int j = 0; j < 4; ++j) {
          accU[i][j] = fmaf(xa[i], na[j], accU[i][j]);
          accC[i][j] = fmaf(xa[i], ca[j], accC[i][j]);
        }
    }
    __syncthreads();
  }
#pragma unroll
  for (int i = 0; i < 4; ++i) {
    const size_t base2 = ((size_t)(b << 10) + n0 + tn + i) * O + o0 + to;
    *(float4*)&U[base2] = make_float4(accU[i][0], accU[i][1], accU[i][2], accU[i][3]);
    *(float4*)&Vd[base2] = make_float4(accC[i][0] - accU[i][0], accC[i][1] - accU[i][1],
                                       accC[i][2] - accU[i][2], accC[i][3] - accU[i][3]);
  }
}

// ---------------------------------------------------------------------------
// edge gather pass (XCD batch affinity: block bx serves batch bx&7).
// Grid 512 (atomic-tail-pinned); stats banked 8-ways by (bx&7).
// ---------------------------------------------------------------------------
template <int O>
__global__ __launch_bounds__(256) void edge_pass_kernel(
    const float* __restrict__ U, const float* __restrict__ Vd,
    const int* __restrict__ idxb, const float* __restrict__ g,
    float* __restrict__ stats, float* __restrict__ ysel) {
  constexpr int PSUB = 256 / O;
  __shared__ float s_red[256];
  const int t = threadIdx.x;
  const int o = t & (O - 1);
  const int psub = t / O;
  const bool usemax = g[o] >= 0.f;
  const int bsel = blockIdx.x & 7;            // batch == presumed XCD
  const int wb = blockIdx.x >> 3;             // 0..63 within batch
  float* st1 = stats + bsel * 256;            // banked partials
  float* st2 = stats + 2048 + bsel * 256;
  const float* ub = U + ((size_t)(bsel << 10)) * O;
  float ls1 = 0.f, ls2 = 0.f;
  for (int pl = wb * PSUB + psub; pl < NN; pl += 64 * PSUB) {
    const int p = (bsel << 10) + pl;
    int id[KNB];
#pragma unroll
    for (int k = 0; k < KNB; ++k) id[k] = idxb[p * KNB + k];
    const float vd = Vd[(size_t)p * O + o];
    float ymx = -3.4e38f, ymn = 3.4e38f;
#pragma unroll
    for (int k = 0; k < KNB; ++k) {
      const float y = ub[(size_t)id[k] * O + o] + vd;
      ymx = fmaxf(ymx, y);
      ymn = fminf(ymn, y);
      ls1 += y;
      ls2 = fmaf(y, y, ls2);
    }
    ysel[(size_t)p * O + o] = usemax ? ymx : ymn;
  }
  if (PSUB == 1) {
    atomicAdd(&st1[o], ls1);
    atomicAdd(&st2[o], ls2);
  } else {
    s_red[t] = ls1;
    __syncthreads();
    if (t < O) {
      float s = s_red[t];
#pragma unroll
      for (int p2 = 1; p2 < PSUB; ++p2) s += s_red[t + p2 * O];
      atomicAdd(&st1[t], s);
    }
    __syncthreads();
    s_red[t] = ls2;
    __syncthreads();
    if (t < O) {
      float s = s_red[t];
#pragma unroll
      for (int p2 = 1; p2 < PSUB; ++p2) s += s_red[t + p2 * O];
      atomicAdd(&st2[t], s);
    }
  }
}

// ---------------------------------------------------------------------------
// bn_apply (finalize inlined, sums 8 stats banks) + transpose; packed bf16
// write for conv1d MFMA. hout may be null (stage 4 MFMA path: dead store).
// ---------------------------------------------------------------------------
template <int O>
__global__ __launch_bounds__(256) void bn_apply_kernel(
    const float* __restrict__ ysel, const float* __restrict__ stats,
    const float* __restrict__ g, const float* __restrict__ bb,
    float* __restrict__ hout, unsigned short* __restrict__ hp, int coff) {
  constexpr int OT = O / 32;
  __shared__ float s_t[32][33];
  const int t = threadIdx.x;
  const int bx = blockIdx.x;
  const int b = bx / (32 * OT);
  const int r = bx % (32 * OT);
  const int n0 = (r / OT) * 32;
  const int o0 = (r % OT) * 32;
  const int col = t & 31, rowb = t >> 5;
  const int o = o0 + col;
  const float inv = 1.f / (8.f * 1024.f * 20.f);
  float sum1 = 0.f, sum2 = 0.f;
#pragma unroll
  for (int j = 0; j < 8; ++j) {
    sum1 += stats[j * 256 + o];
    sum2 += stats[2048 + j * 256 + o];
  }
  const float mean = sum1 * inv;
  const float var = sum2 * inv - mean * mean;
  const float sc = g[o] * rsqrtf(var + BNEPS);
  const float sh = bb[o] - mean * sc;
  const int c = coff + o;               // conv1d K index
#pragma unroll
  for (int rr = 0; rr < 4; ++rr) {
    const int nl = n0 + rowb + rr * 8;
    const float y = ysel[((size_t)(b << 10) + nl) * O + o];
    const float h = lrelu(fmaf(sc, y, sh));
    if (hout) s_t[rowb + rr * 8][col] = h;
    if (hp) {
      const int lane2 = (nl & 31) + ((c >> 3) & 1) * 32;
      hp[(((size_t)(b * 32 + (nl >> 5)) * 32 + (c >> 4)) * 64 + lane2) * 8 +
         (c & 7)] = f2b(h);
    }
  }
  if (hout) {
    __syncthreads();
#pragma unroll
    for (int rr = 0; rr < 4; ++rr) {
      const int ol = rowb + rr * 8;
      hout[(size_t)b * (512 * 1024) + (o0 + ol) * NN + n0 + col] = s_t[col][ol];
    }
  }
}

// ---------------------------------------------------------------------------
// conv1d via MFMA on packed fragments: Y5[b][o][n] = sum_c W5[o][c]*h[b][n][c]
// ---------------------------------------------------------------------------
__global__ __launch_bounds__(256) void conv1d_mfma_kernel(
    const unsigned short* __restrict__ hp,
    const unsigned short* __restrict__ w5p, float* __restrict__ Y5) {
  const int t = threadIdx.x, bx = blockIdx.x;
  const int b = bx >> 6;
  const int r = bx & 63;
  const int w = t >> 6, lane = t & 63;
  const int ot0 = (r >> 3) * 4 + (w & 1) * 2;
  const int nt0 = (r & 7) * 4 + (w >> 1) * 2;
  const unsigned short* a0p = w5p + (size_t)ot0 * 16384 + lane * 8;
  const unsigned short* a1p = a0p + 16384;
  const unsigned short* b0p = hp + (size_t)(b * 32 + nt0) * 16384 + lane * 8;
  const unsigned short* b1p = b0p + 16384;
  f32x16 acc00, acc01, acc10, acc11;
#pragma unroll
  for (int i = 0; i < 16; ++i) { acc00[i] = 0.f; acc01[i] = 0.f; acc10[i] = 0.f; acc11[i] = 0.f; }
#pragma unroll 2
  for (int kb = 0; kb < 32; ++kb) {
    const int off = kb * 512;
    const short8v a0 = *(const short8v*)(a0p + off);
    const short8v a1 = *(const short8v*)(a1p + off);
    const short8v b0 = *(const short8v*)(b0p + off);
    const short8v b1 = *(const short8v*)(b1p + off);
    acc00 = __builtin_amdgcn_mfma_f32_32x32x16_bf16(a0, b0, acc00, 0, 0, 0);
    acc01 = __builtin_amdgcn_mfma_f32_32x32x16_bf16(a0, b1, acc01, 0, 0, 0);
    acc10 = __builtin_amdgcn_mfma_f32_32x32x16_bf16(a1, b0, acc10, 0, 0, 0);
    acc11 = __builtin_amdgcn_mfma_f32_32x32x16_bf16(a1, b1, acc11, 0, 0, 0);
  }
  const int l31 = lane & 31, l5 = lane >> 5;
#pragma unroll
  for (int oi = 0; oi < 2; ++oi) {
#pragma unroll
    for (int nj = 0; nj < 2; ++nj) {
      const f32x16 a = (oi == 0) ? (nj == 0 ? acc00 : acc01)
                                 : (nj == 0 ? acc10 : acc11);
      const int ob = (ot0 + oi) * 32;
      const int nb = (nt0 + nj) * 32;
#pragma unroll
      for (int r16 = 0; r16 < 16; ++r16) {
        const int row = (r16 & 3) + 8 * (r16 >> 2) + 4 * l5;
        Y5[((size_t)(b << 10) + ob + row) * 1024 + nb + l31] = a[r16];
      }
    }
  }
}

// ---------------------------------------------------------------------------
// c1pool: one block per channel o; single HBM pass (rows staged in LDS).
// ---------------------------------------------------------------------------
__global__ __launch_bounds__(256) void c1pool_kernel(
    const float* __restrict__ Y5, const float* __restrict__ g,
    const float* __restrict__ bb, float* __restrict__ z) {
  __shared__ __align__(16) float s_y[8][1024];
  __shared__ float sr[256];
  __shared__ float s_par[2];
  const int o = blockIdx.x, t = threadIdx.x;
  float s1 = 0.f, s2 = 0.f;
#pragma unroll
  for (int b = 0; b < 8; ++b) {
    const float4 v = *(const float4*)&Y5[((size_t)((b << 10) + o)) * 1024 + t * 4];
    *(float4*)&s_y[b][t * 4] = v;
    s1 += v.x + v.y + v.z + v.w;
    s2 = fmaf(v.x, v.x, s2);
    s2 = fmaf(v.y, v.y, s2);
    s2 = fmaf(v.z, v.z, s2);
    s2 = fmaf(v.w, v.w, s2);
  }
  sr[t] = s1;
  __syncthreads();
  for (int s = 128; s > 0; s >>= 1) {
    if (t < s) sr[t] += sr[t + s];
    __syncthreads();
  }
  if (t == 0) s_par[0] = sr[0];
  __syncthreads();
  sr[t] = s2;
  __syncthreads();
  for (int s = 128; s > 0; s >>= 1) {
    if (t < s) sr[t] += sr[t + s];
    __syncthreads();
  }
  if (t == 0) {
    const float mean = s_par[0] * (1.f / 8192.f);
    const float var = sr[0] * (1.f / 8192.f) - mean * mean;
    const float sc = g[o] * rsqrtf(var + BNEPS);
    s_par[0] = sc;
    s_par[1] = bb[o] - mean * sc;
  }
  __syncthreads();
  const float sc = s_par[0], sh = s_par[1];
  const int lane = t & 63, w = t >> 6;
#pragma unroll
  for (int h = 0; h < 2; ++h) {
    const int b = w + h * 4;
    float mx = -3.4e38f, sm = 0.f;
#pragma unroll
    for (int j = 0; j < 4; ++j) {
      const float4 v = *(const float4*)&s_y[b][lane * 16 + j * 4];
      const float y0 = lrelu(fmaf(sc, v.x, sh));
      const float y1 = lrelu(fmaf(sc, v.y, sh));
      const float y2 = lrelu(fmaf(sc, v.z, sh));
      const float y3 = lrelu(fmaf(sc, v.w, sh));
      mx = fmaxf(fmaxf(fmaxf(mx, y0), fmaxf(y1, y2)), y3);
      sm += y0 + y1 + y2 + y3;
    }
#pragma unroll
    for (int off = 1; off < 64; off <<= 1) {
      mx = fmaxf(mx, __shfl_xor(mx, off, 64));
      sm += __shfl_xor(sm, off, 64);
    }
    if (lane == 0) {
      z[b * 2048 + o] = mx;
      z[b * 2048 + 1024 + o] = sm * (1.f / 1024.f);
    }
  }
}

// ---------------------------------------------------------------------------
// fallback f32 conv1d (used only if ws too small for MFMA buffers)
// ---------------------------------------------------------------------------
__global__ void bn_finalize_kernel(float* __restrict__ stats,
                                   const float* __restrict__ g,
                                   const float* __restrict__ bb, int cout,
                                   float inv_cnt) {
  const int o = blockIdx.x * 256 + threadIdx.x;
  if (o >= cout) return;
  const float mean = stats[o] * inv_cnt;
  const float var = stats[1024 + o] * inv_cnt - mean * mean;
  const float s = g[o] * rsqrtf(var + BNEPS);
  stats[2048 + o] = s;
  stats[3072 + o] = bb[o] - mean * s;
}

__global__ __launch_bounds__(256) void conv1d_gemm_kernel(
    const float* __restrict__ hcat, const float* __restrict__ WT5,
    float* __restrict__ stats, float* __restrict__ Y5) {
  __shared__ __align__(16) float s_w[8][64];
  __shared__ __align__(16) float s_h[8][64];
  __shared__ __align__(16) float s_red[64][16];
  const int t = threadIdx.x;
  const int bx = blockIdx.x;
  const int b = bx >> 8;
  const int o0 = ((bx >> 4) & 15) * 64;
  const int n0 = (bx & 15) * 64;
  const float* hb = hcat + (size_t)b * (512 * 1024);
  const int to = (t >> 4) * 4;
  const int tn = (t & 15) * 4;
  float acc[4][4] = {};
  for (int c0 = 0; c0 < 512; c0 += 8) {
    for (int i = t; i < 8 * 64; i += 256) {
      const int cc = i >> 6, col = i & 63;
      s_w[cc][col] = WT5[(c0 + cc) * 1024 + o0 + col];
      s_h[cc][col] = hb[(c0 + cc) * NN + n0 + col];
    }
    __syncthreads();
#pragma unroll
    for (int cc = 0; cc < 8; ++cc) {
      const float4 wv = *(const float4*)&s_w[cc][to];
      const float4 hv = *(const float4*)&s_h[cc][tn];
      const float wa[4] = {wv.x, wv.y, wv.z, wv.w};
      const float ha[4] = {hv.x, hv.y, hv.z, hv.w};
#pragma unroll
      for (int i = 0; i < 4; ++i)
#pragma unroll
        for (int j = 0; j < 4; ++j) acc[i][j] = fmaf(wa[i], ha[j], acc[i][j]);
    }
    __syncthreads();
  }
#pragma unroll
  for (int i = 0; i < 4; ++i) {
    *(float4*)&Y5[((size_t)(b << 10) + o0 + to + i) * NN + n0 + tn] =
        make_float4(acc[i][0], acc[i][1], acc[i][2], acc[i][3]);
  }
#pragma unroll
  for (int i = 0; i < 4; ++i)
    s_red[to + i][t & 15] = acc[i][0] + acc[i][1] + acc[i][2] + acc[i][3];
  __syncthreads();
  if (t < 64) {
    float s = 0.f;
#pragma unroll
    for (int g2 = 0; g2 < 16; ++g2) s += s_red[t][g2];
    atomicAdd(&stats[o0 + t], s);
  }
  __syncthreads();
#pragma unroll
  for (int i = 0; i < 4; ++i) {
    float s = 0.f;
#pragma unroll
    for (int j = 0; j < 4; ++j) s = fmaf(acc[i][j], acc[i][j], s);
    s_red[to + i][t & 15] = s;
  }
  __syncthreads();
  if (t < 64) {
    float s = 0.f;
#pragma unroll
    for (int g2 = 0; g2 < 16; ++g2) s += s_red[t][g2];
    atomicAdd(&stats[1024 + o0 + t], s);
  }
}

__global__ __launch_bounds__(256) void pool_kernel(
    const float* __restrict__ Y5, const float* __restrict__ stats,
    float* __restrict__ z) {
  const int t = threadIdx.x;
  const int lane = t & 63;
  const int bx = blockIdx.x;
  const int b = bx >> 8;
  const int o = (bx & 255) * 4 + (t >> 6);
  const float sc = stats[2048 + o], sh = stats[3072 + o];
  const float* yr = Y5 + ((size_t)(b << 10) + o) * NN;
  float mx = -3.4e38f, sm = 0.f;
#pragma unroll
  for (int j = 0; j < 16; ++j) {
    const float y = lrelu(fmaf(sc, yr[j * 64 + lane], sh));
    mx = fmaxf(mx, y);
    sm += y;
  }
  for (int off = 32; off > 0; off >>= 1) {
    mx = fmaxf(mx, __shfl_down(mx, off, 64));
    sm += __shfl_down(sm, off, 64);
  }
  if (lane == 0) {
    z[b * 2048 + o] = mx;
    z[b * 2048 + 1024 + o] = sm * (1.f / 1024.f);
  }
}

// ---------------------------------------------------------------------------
// MLP layer with batch-of-8 BN + lrelu fused. W/bias read RAW from inputs.
// ---------------------------------------------------------------------------
__global__ __launch_bounds__(256) void mlp_kernel(
    const float* __restrict__ zin, const void* __restrict__ W,
    const void* __restrict__ bias, const int* __restrict__ flags, int wfl,
    int bfl, const float* __restrict__ g, const float* __restrict__ bb,
    int kin, float* __restrict__ out, int O) {
  __shared__ float s_red[256];
  __shared__ float s_y[8];
  const int t = threadIdx.x;
  const int o = blockIdx.x;
  const int fw = flags[wfl];
  float acc[8];
#pragma unroll
  for (int b = 0; b < 8; ++b) acc[b] = 0.f;
  for (int c = t; c < kin; c += 256) {
    const float w = load_in(W, fw, o * kin + c);
#pragma unroll
    for (int b = 0; b < 8; ++b) acc[b] = fmaf(w, zin[b * kin + c], acc[b]);
  }
  for (int b = 0; b < 8; ++b) {
    s_red[t] = acc[b];
    __syncthreads();
    for (int s = 128; s > 0; s >>= 1) {
      if (t < s) s_red[t] += s_red[t + s];
      __syncthreads();
    }
    if (t == 0)
      s_y[b] = s_red[0] + (bias ? load_in(bias, flags[bfl], o) : 0.f);
    __syncthreads();
  }
  if (t == 0) {
    float m = 0.f;
    for (int b = 0; b < 8; ++b) m += s_y[b];
    m *= 0.125f;
    float v = 0.f;
    for (int b = 0; b < 8; ++b) { const float d = s_y[b] - m; v = fmaf(d, d, v); }
    v *= 0.125f;
    const float s = g[o] * rsqrtf(v + BNEPS);
    const float sh = bb[o] - m * s;
    for (int b = 0; b < 8; ++b) out[b * O + o] = lrelu(fmaf(s, s_y[b], sh));
  }
}

// final: out = z2 @ Wl3^T + bl3 (raw reads); output dtype from flags.
__global__ void final_kernel(const float* __restrict__ z2,
                             const void* __restrict__ Wl3,
                             const void* __restrict__ bl3,
                             const int* __restrict__ flags, void* out) {
  const int j = blockIdx.x * 256 + threadIdx.x;
  if (j >= 320) return;
  int anyf32 = 0, anybf = 0;
  for (int i = 0; i < NIN; ++i) {
    const int fl = flags[i];
    if (fl == 0) anyf32 = 1;
    if (fl == 1) anybf = 1;
  }
  const int bf16out = (anybf && !anyf32) ? 1 : 0;
  const int fw = flags[9], fb = flags[10];
  const int b = j / 40, o = j - b * 40;
  float s = load_in(bl3, fb, o);
  for (int c = 0; c < 256; ++c)
    s = fmaf(z2[b * 256 + c], load_in(Wl3, fw, o * 256 + c), s);
  if (bf16out) ((__hip_bfloat16*)out)[j] = __float2bfloat16(s);
  else ((float*)out)[j] = s;
}

// ---------------------------------------------------------------------------
template <int C, int O>
static void run_stage(float* wsf, const float* xbase, int bstr, int widx,
                      int gidx, int bidx, int stat, float* hout,
                      unsigned short* hp, int coff, hipStream_t stream) {
  int* idxb = reinterpret_cast<int*>(wsf + IDXo);
  float* U = wsf + U_OFF;
  float* Vd = wsf + VD_OFF;
  float* ysel = wsf + YS_OFF;
  float* stats = wsf + STATSo + stat * 4096;
  tg_kernel<C, O><<<1024 + BB * 16 * (O / 64), 256, 0, stream>>>(
      xbase, bstr, wsf + widx, U, Vd, idxb);
  edge_pass_kernel<O><<<512, 256, 0, stream>>>(U, Vd, idxb, wsf + gidx, stats,
                                               ysel);
  bn_apply_kernel<O><<<BB * 32 * (O / 32), 256, 0, stream>>>(
      ysel, stats, wsf + gidx, wsf + bidx, hout, hp, coff);
}

extern "C" void kernel_launch(void* const* d_in, const int* in_sizes, int n_in,
                              void* d_out, int out_size, void* d_ws,
                              size_t ws_size, hipStream_t stream) {
  (void)in_sizes; (void)n_in; (void)out_size;
  float* wsf = reinterpret_cast<float*>(d_ws);
  int* flags = reinterpret_cast<int*>(wsf + FLAGSo);
  float* hcat = wsf + HCATo;
  const bool mf = ws_size >= WS_NEED_MFMA;
  unsigned short* hp = mf ? reinterpret_cast<unsigned short*>(wsf + HBFo) : nullptr;
  unsigned short* w5p = reinterpret_cast<unsigned short*>(wsf + W5BFo);

  Ptrs ptrs;
  for (int i = 0; i < NIN; ++i) ptrs.p[i] = d_in[i];

  detect_kernel<<<NIN, 64, 0, stream>>>(ptrs, flags);
  const int nmain = mf ? NMAIN_MF : NCONV;
  convert_kernel<<<nmain + 80 + 256, 256, 0, stream>>>(ptrs, flags, wsf,
                                                       mf ? 1 : 0, nmain);

  run_stage<3, 64>(wsf, wsf + XIN, 3 * NN, WT1, G1, B1o, 0, hcat, hp, 0,
                   stream);
  run_stage<64, 64>(wsf, hcat, 512 * NN, WT2, G2, B2o, 1, hcat + 64 * NN, hp,
                    64, stream);
  run_stage<64, 128>(wsf, hcat + 64 * NN, 512 * NN, WT3, G3, B3o, 2,
                     hcat + 128 * NN, hp, 128, stream);
  // stage 4: f32 hout is dead in the MFMA path (only packed hp consumed)
  run_stage<128, 256>(wsf, hcat + 128 * NN, 512 * NN, WT4, G4, B4o, 3,
                      mf ? nullptr : (hcat + 256 * NN), hp, 256, stream);

  // conv1d 512->1024 + BN + pool
  float* Y5 = wsf + Y5_OFF;
  float* st5 = wsf + STATSo + 4 * 4096;
  if (mf) {
    conv1d_mfma_kernel<<<512, 256, 0, stream>>>(hp, w5p, Y5);
    c1pool_kernel<<<1024, 256, 0, stream>>>(Y5, wsf + G5, wsf + B5o,
                                            wsf + Z2048o);
  } else {
    conv1d_gemm_kernel<<<2048, 256, 0, stream>>>(hcat, wsf + WT5, st5, Y5);
    bn_finalize_kernel<<<4, 256, 0, stream>>>(st5, wsf + G5, wsf + B5o, 1024,
                                              1.f / 8192.f);
    pool_kernel<<<BB * 256, 256, 0, stream>>>(Y5, st5, wsf + Z2048o);
  }

  // MLP head (raw W/bias reads)
  mlp_kernel<<<512, 256, 0, stream>>>(wsf + Z2048o, d_in[6], nullptr, flags,
      6, 0, wsf + G6, wsf + B6o, 2048, wsf + Z1o, 512);
  mlp_kernel<<<256, 256, 0, stream>>>(wsf + Z1o, d_in[7], d_in[8], flags,
      7, 8, wsf + G7, wsf + B7o, 512, wsf + Z2o, 256);
  final_kernel<<<2, 256, 0, stream>>>(wsf + Z2o, d_in[9], d_in[10],
      flags, d_out);
}

// Round 16
// 432.534 us; speedup vs baseline: 1.0393x; 1.0393x over previous
//
#include <hip/hip_runtime.h>
#include <hip/hip_bf16.h>
#include <cstdint>

// ---------------------------------------------------------------------------
// DGCNN forward on MI355X. Math f32; conv1d via bf16 MFMA on packed
// fragment layouts; kNN via FUSED dist+topk.
// R29: interleave the 4 per-wave topk binary searches. Evidence: tg ~85us
// for ALL stages incl. C=3 -> topk tail dominates; occ 20% (2 waves/SIMD,
// wave-scarce) -> the 4-row-serial 32-iter ballot search (128 dependent
// cmp/ballot/popc links) is the chain. R28's occupancy route regressed
// (staging work doubled). Now: compute k16a[4][16] for all rows (acc dead
// after -> regs reused), then ONE 32-iter loop with 4 independent ballots
// per iter (T4[4]); compact/rank tails stay per-row. Identical keys +
// independent per-row searches -> identical idxb -> absmax canary
// 0.02050781. Base = R27: 16 rows/block, 512 fused blocks, conflict-free
// col ownership {lane+64j}. Kept: banked stats atomics + 8-bank bn sum,
// edge XCD batch affinity, convert compaction + raw MLP reads, c1pool
// single-pass, stage-4 hout skip.
// ---------------------------------------------------------------------------

static constexpr int BB  = 8;
static constexpr int NN  = 1024;
static constexpr int KNB = 20;
static constexpr float BNEPS = 1e-5f;

static constexpr int NIN = 25;

__constant__ int c_cum[NIN + 1] = {
    0, 24576, 24960, 33152, 49536, 115072, 639360,
    1687936, 1819008, 1819264, 1829504, 1829544, 1829608, 1829672, 1829736,
    1829800, 1829928, 1830056, 1830312, 1830568, 1831592, 1832616, 1833128,
    1833640, 1833896, 1834152};
__constant__ int c_trO[NIN] = {0, 64, 64, 128, 256, 1024, 0, 0, 0, 0, 0,
                               0, 0, 0, 0, 0, 0, 0, 0, 0, 0, 0, 0, 0, 0};
__constant__ int c_trI[NIN] = {0, 6, 128, 128, 256, 512, 0, 0, 0, 0, 0,
                               0, 0, 0, 0, 0, 0, 0, 0, 0, 0, 0, 0, 0, 0};

enum : int {
  XIN = 0, WT1 = 24576, WT2 = 24960, WT3 = 33152, WT4 = 49536, WT5 = 115072,
  WL1 = 639360, WL2 = 1687936, BL2o = 1819008, WL3 = 1819264, BL3o = 1829504,
  G1 = 1829544, B1o = 1829608, G2 = 1829672, B2o = 1829736,
  G3 = 1829800, B3o = 1829928, G4 = 1830056, B4o = 1830312,
  G5 = 1830568, B5o = 1831592, G6 = 1832616, B6o = 1833128,
  G7 = 1833640, B7o = 1833896,
  IDXo = 1842432,       // 163840 i32
  HCATo = 2006272,      // 8*512*1024 f
  STATSo = 6200576,     // 5 layers * 4096 f (stages 0-3: 8-banked partials)
  Z2048o = 6237440,     // 8*2048 f
  Z1o = 6253824,        // 8*512 f
  Z2o = 6257920,        // 8*256 f
  FLAGSo = 6259968,     // 32 i32
  DISTo = 6260736,      // window (U/Vd/ysel; D not materialized)
  HBFo  = 14649344,     // packed bf16 h: 8*1024*512 shorts (2M float slots)
  W5BFo = 16746496      // packed bf16 w5: 512K shorts -> ends 17008640
};
static constexpr int TOTAL_IN = 1834152;
static constexpr int NCONV = (TOTAL_IN + 255) / 256;   // full-copy blocks (!mf)
static constexpr int NMAIN_ELEMS = 115072 + 4608;      // 119680
static constexpr int NMAIN_MF = (NMAIN_ELEMS + 255) / 256;  // 468 blocks
static constexpr int U_OFF   = DISTo + 0;
static constexpr int VD_OFF  = DISTo + 2097152;
static constexpr int YS_OFF  = DISTo + 4194304;
static constexpr int Y5_OFF  = DISTo + 0;
static constexpr size_t WS_NEED_MFMA = (size_t)17008640 * 4;  // ~68 MB

struct Ptrs { const void* p[NIN]; };

typedef short short8v __attribute__((ext_vector_type(8)));
typedef float f32x16 __attribute__((ext_vector_type(16)));

__device__ __forceinline__ float lrelu(float y) { return (y < 0.f) ? 0.2f * y : y; }
__device__ __forceinline__ unsigned short f2b(float f) {
  unsigned u = __float_as_uint(f);
  unsigned r = (u + 0x7FFFu + ((u >> 16) & 1u)) >> 16;   // RNE
  return (unsigned short)r;
}
// sortable key: monotone map float -> u32 (larger float -> larger key)
__device__ __forceinline__ unsigned f2s(float f) {
  const unsigned s = __float_as_uint(f);
  return s ^ ((unsigned)((int)s >> 31) | 0x80000000u);
}
__device__ __forceinline__ float load_in(const void* p, int fl, int idx) {
  if (fl == 2) return 0.f;
  if (fl == 1) {
    const unsigned short u = ((const unsigned short*)p)[idx];
    return __uint_as_float(((unsigned)u) << 16);
  }
  return ((const float*)p)[idx];
}
__device__ __forceinline__ int mbcnt64(unsigned long long m) {
  return __builtin_amdgcn_mbcnt_hi((unsigned)(m >> 32),
                                   __builtin_amdgcn_mbcnt_lo((unsigned)m, 0));
}

// ---------------------------------------------------------------------------
// dtype detection
// ---------------------------------------------------------------------------
__global__ void detect_kernel(Ptrs ptrs, int* __restrict__ flags) {
  const int i = blockIdx.x;
  const unsigned* p = (const unsigned*)ptrs.p[i];
  const int n = c_cum[i + 1] - c_cum[i];
  int words = n >> 1; if (words > 64) words = 64;
  const int t = threadIdx.x;
  unsigned w = (t < words) ? p[t] : 0u;
  bool nz = (w != 0u);
  unsigned e = (w >> 7) & 0xFFu;
  bool pl = nz && (e >= 96u) && (e <= 140u);
  unsigned long long mnz = __ballot(nz);
  unsigned long long mpl = __ballot(pl);
  if (t == 0) {
    int cnz = __popcll(mnz), cpl = __popcll(mpl);
    flags[i] = (cnz == 0) ? 2 : ((2 * cpl > words) ? 1 : 0);
  }
}

// ---------------------------------------------------------------------------
// convert: main blocks convert+transpose inputs; tail1 zeroes stats;
// tail2 packs w5 (raw input -> MFMA A-fragment bf16) if do_w5.
// ---------------------------------------------------------------------------
__global__ void convert_kernel(Ptrs ptrs, const int* __restrict__ flags,
                               float* __restrict__ ws, int do_w5, int nmain) {
  const int bx = blockIdx.x;
  const int t = threadIdx.x;
  if (bx >= nmain + 80) {            // tail2: w5 packing
    if (!do_w5) return;
    const int g = (bx - nmain - 80) * 256 + t;   // 0..65535
    const int lane = g & 63;
    const int kb = (g >> 6) & 31;
    const int ot = g >> 11;
    const int o = ot * 32 + (lane & 31);
    const int k0 = kb * 16 + (lane >> 5) * 8;
    const void* w5raw = ptrs.p[5];
    const int fl = flags[5];
    unsigned u[4];
#pragma unroll
    for (int h = 0; h < 4; ++h) {
      const unsigned short lo = f2b(load_in(w5raw, fl, o * 512 + k0 + 2 * h));
      const unsigned short hi = f2b(load_in(w5raw, fl, o * 512 + k0 + 2 * h + 1));
      u[h] = (unsigned)lo | ((unsigned)hi << 16);
    }
    unsigned short* w5p = (unsigned short*)(ws + W5BFo);
    *(uint4*)&w5p[(size_t)g * 8] = make_uint4(u[0], u[1], u[2], u[3]);
    return;
  }
  if (bx >= nmain) {                 // tail1: zero stats
    const int z = (bx - nmain) * 256 + t;
    if (z < 20480) ws[STATSo + z] = 0.f;
    return;
  }
  int e;
  if (do_w5) {                       // compact map
    const int e2 = bx * 256 + t;
    if (e2 >= NMAIN_ELEMS) return;
    e = (e2 < 115072) ? e2 : (e2 - 115072 + 1829544);
  } else {
    e = bx * 256 + t;
    if (e >= TOTAL_IN) return;
  }
  int i = 0;
  while (e >= c_cum[i + 1]) ++i;
  const int el = e - c_cum[i];
  int src;
  const int O = c_trO[i];
  if (O > 0) {
    const int I = c_trI[i];
    const int o = el % O, ii = el / O;
    src = o * I + ii;
  } else src = el;
  ws[e] = load_in(ptrs.p[i], flags[i], src);
}

// ---------------------------------------------------------------------------
// merged FUSED dist+topk (blocks 0..511) + gemm_uv (blocks 512..).
// Lane owns cols {lane + 64j, j=0..15}: LDS reads bank = lane%32 -> free.
// topk: keys for all 4 rows computed first; 32-iter binary search runs 4
// rows INTERLEAVED (4 independent ballots/iter); tails per-row.
// ---------------------------------------------------------------------------
template <int C, int O>
__global__ __launch_bounds__(256) void tg_kernel(
    const float* __restrict__ xbase, int bstr, const float* __restrict__ WT,
    float* __restrict__ U, float* __restrict__ Vd, int* __restrict__ idxb) {
  constexpr int OT = O / 64;
  __shared__ __align__(16) float s_mem[8 * 1024 + 128 + 1024];
  const int t = threadIdx.x;
  if (blockIdx.x < 512) {
    float (*s_b)[1024] = (float(*)[1024])s_mem;
    float (*s_a)[8] = (float(*)[8])(s_mem + 8192);
    float* s_xx = s_mem + 8192 + 128;
    const int b = blockIdx.x & 7;          // batch (XCD-affine)
    const int rg = blockIdx.x >> 3;        // 0..63
    const int r0 = rg * 16;
    const float* xb = xbase + (size_t)b * bstr;
    const int wv = t >> 6, lane = t & 63;
    float acc[4][16] = {};
    float xxa[4] = {0.f, 0.f, 0.f, 0.f};
    for (int c0 = 0; c0 < C; c0 += 8) {
      const int kc = (C - c0 < 8) ? (C - c0) : 8;
      __syncthreads();
      for (int i = t; i < 2048; i += 256) {          // B: [8][1024] (zero-pad)
        const int cc = i >> 8, col4 = (i & 255) * 4;
        float4 v = make_float4(0.f, 0.f, 0.f, 0.f);
        if (cc < kc) v = *(const float4*)&xb[(c0 + cc) * NN + col4];
        *(float4*)&s_b[cc][col4] = v;
      }
      if (t < 128) {                                  // A: [16][8]
        const int rr = t >> 3, cc = t & 7;
        s_a[rr][cc] = (cc < kc) ? xb[(c0 + cc) * NN + r0 + rr] : 0.f;
      }
      __syncthreads();
#pragma unroll
      for (int cc = 0; cc < 8; ++cc) {
        float a4[4];
#pragma unroll
        for (int ri = 0; ri < 4; ++ri) a4[ri] = s_a[wv * 4 + ri][cc];
        float bv[16];
#pragma unroll
        for (int j = 0; j < 16; ++j) bv[j] = s_b[cc][lane + 64 * j];
#pragma unroll
        for (int ri = 0; ri < 4; ++ri)
#pragma unroll
          for (int j = 0; j < 16; ++j)
            acc[ri][j] = fmaf(a4[ri], bv[j], acc[ri][j]);
#pragma unroll
        for (int q = 0; q < 4; ++q) {                // col-norm partials
          const float v = s_b[cc][q * 256 + t];
          xxa[q] = fmaf(v, v, xxa[q]);
        }
      }
    }
    __syncthreads();
#pragma unroll
    for (int q = 0; q < 4; ++q) s_xx[q * 256 + t] = xxa[q];
    __syncthreads();
    float xm[16];
#pragma unroll
    for (int j = 0; j < 16; ++j) xm[j] = s_xx[lane + 64 * j];
    unsigned long long* scw = (unsigned long long*)s_mem + wv * 128;
    // ---- keys for all 4 rows (acc dead after -> regs reused) ----
    unsigned k16a[4][16];
    unsigned lmax4[4];
#pragma unroll
    for (int ri = 0; ri < 4; ++ri) {
      const float xxn = s_xx[r0 + wv * 4 + ri];
      unsigned lm = 0u;
#pragma unroll
      for (int j = 0; j < 16; ++j) {
        k16a[ri][j] = f2s(2.f * acc[ri][j] - xxn - xm[j]);
        lm = (k16a[ri][j] > lm) ? k16a[ri][j] : lm;
      }
      lmax4[ri] = lm;
    }
    // ---- interleaved binary search: 4 independent ballots per iter ----
    unsigned T4[4] = {0u, 0u, 0u, 0u};
    for (int bb2 = 31; bb2 >= 0; --bb2) {
#pragma unroll
      for (int ri = 0; ri < 4; ++ri) {
        const unsigned cand = T4[ri] | (1u << bb2);
        if (__popcll(__ballot(lmax4[ri] >= cand)) >= KNB) T4[ri] = cand;
      }
    }
    // ---- per-row tails (compact / rank / scatter) ----
#pragma unroll
    for (int ri = 0; ri < 4; ++ri) {     // UNROLLED: static indices (rule #20)
      const int rowg = (b << 10) + r0 + wv * 4 + ri;
      const unsigned T = T4[ri];
      int cnt = 0;
#pragma unroll
      for (int j = 0; j < 16; ++j) cnt += (k16a[ri][j] >= T) ? 1 : 0;
      int n_c = 0, off = 0;
#pragma unroll
      for (int bb2 = 0; bb2 < 5; ++bb2) {
        const unsigned long long m = __ballot((cnt >> bb2) & 1);
        n_c += __popcll(m) << bb2;
        off += mbcnt64(m) << bb2;
      }
      if (n_c <= 128) {
#pragma unroll
        for (int j = 0; j < 16; ++j)
          if (k16a[ri][j] >= T) {
            const int ci = lane + 64 * j;
            scw[off] = (((unsigned long long)k16a[ri][j]) << 32) |
                       (unsigned long long)(0xFFFFFFFFu ^ (unsigned)ci);
            ++off;
          }
        if (n_c <= 64) {
          unsigned long long mye = 0ULL;
          if (lane < n_c) mye = scw[lane];
          int rank = 0;
          for (int j = 0; j < n_c; ++j) {
            const unsigned eh =
                (unsigned)__builtin_amdgcn_readlane((int)(mye >> 32), j);
            const unsigned el =
                (unsigned)__builtin_amdgcn_readlane((int)(mye & 0xFFFFFFFFu), j);
            const unsigned long long ej = (((unsigned long long)eh) << 32) | el;
            rank += (ej > mye) ? 1 : 0;
          }
          if (lane < n_c && rank < KNB)
            idxb[rowg * KNB + rank] =
                (int)(0xFFFFFFFFu ^ (unsigned)(mye & 0xFFFFFFFFu));
        } else {
          const unsigned long long mye = (lane < n_c) ? scw[lane] : 0ULL;
          const unsigned long long mye2 =
              (64 + lane < n_c) ? scw[64 + lane] : 0ULL;
          int r1 = 0, r2 = 0;
          for (int j = 0; j < n_c; ++j) {
            const unsigned long long ej = scw[j];   // broadcast read
            r1 += (ej > mye) ? 1 : 0;
            r2 += (ej > mye2) ? 1 : 0;
          }
          if (lane < n_c && r1 < KNB)
            idxb[rowg * KNB + r1] = (int)(0xFFFFFFFFu ^ (unsigned)mye);
          if (64 + lane < n_c && r2 < KNB)
            idxb[rowg * KNB + r2] = (int)(0xFFFFFFFFu ^ (unsigned)mye2);
        }
      } else {
        // ---- composite-u64 extraction fallback (exact; ~never) ----
        unsigned long long q[4] = {0ULL, 0ULL, 0ULL, 0ULL};
        unsigned emit = 0;
#pragma unroll
        for (int j = 0; j < 16; ++j) {
          const int ci = lane + 64 * j;
          const unsigned long long c =
              (((unsigned long long)k16a[ri][j]) << 32) |
              (unsigned long long)(0xFFFFFFFFu ^ (unsigned)ci);
          if (c > q[3]) {
            q[3] = c;
            if (q[3] > q[2]) { auto tv = q[2]; q[2] = q[3]; q[3] = tv; }
            if (q[2] > q[1]) { auto tv = q[1]; q[1] = q[2]; q[2] = tv; }
            if (q[1] > q[0]) { auto tv = q[0]; q[0] = q[1]; q[1] = tv; }
          }
        }
        for (int kk = 0; kk < KNB; ++kk) {
          unsigned long long best = q[0];
          for (int o2 = 1; o2 < 64; o2 <<= 1) {
            const unsigned long long p =
                (unsigned long long)__shfl_xor((long long)best, o2, 64);
            best = (p > best) ? p : best;
          }
          if (lane == 0)
            idxb[rowg * KNB + kk] = (int)(0xFFFFFFFFu ^ (unsigned)best);
          if (q[0] == best) {           // unique owner (idx in composite)
            const int ci = (int)(0xFFFFFFFFu ^ (unsigned)best);
            const int j = (ci - lane) >> 6;
            emit |= 1u << j;
            q[0] = q[1]; q[1] = q[2]; q[2] = q[3]; q[3] = 0ULL;
            if (q[0] == 0ULL && __popc(emit) < 16) {
              for (int j2 = 0; j2 < 16; ++j2)
                if (!((emit >> j2) & 1u)) {
                  const int ci2 = lane + 64 * j2;
                  const unsigned long long c2 =
                      (((unsigned long long)k16a[ri][j2]) << 32) |
                      (unsigned long long)(0xFFFFFFFFu ^ (unsigned)ci2);
                  if (c2 > q[3]) {
                    q[3] = c2;
                    if (q[3] > q[2]) { auto tv = q[2]; q[2] = q[3]; q[3] = tv; }
                    if (q[2] > q[1]) { auto tv = q[1]; q[1] = q[2]; q[2] = tv; }
                    if (q[1] > q[0]) { auto tv = q[0]; q[0] = q[1]; q[1] = tv; }
                  }
                }
            }
          }
        }
      }
    }
    return;
  }
  // ---- gemm_uv part (LDS aliased onto s_mem) ----
  float (*s_x)[64] = (float(*)[64])(s_mem);
  float (*s_wn)[64] = (float(*)[64])(s_mem + 512);
  float (*s_wc)[64] = (float(*)[64])(s_mem + 1024);
  const int bx = blockIdx.x - 512;
  const int b = bx / (16 * OT);
  const int r = bx % (16 * OT);
  const int n0 = (r / OT) * 64;
  const int o0 = (r % OT) * 64;
  const float* xb = xbase + (size_t)b * bstr;
  const int tn = (t >> 4) * 4;
  const int to = (t & 15) * 4;
  float accU[4][4] = {}, accC[4][4] = {};
  for (int c0 = 0; c0 < C; c0 += 8) {
    const int kc = (C - c0 < 8) ? (C - c0) : 8;
    for (int i = t; i < 8 * 64; i += 256) {
      const int cc = i >> 6, col = i & 63;
      const bool ok = cc < kc;
      s_x[cc][col]  = ok ? xb[(c0 + cc) * NN + n0 + col] : 0.f;
      s_wn[cc][col] = ok ? WT[(c0 + cc) * O + o0 + col] : 0.f;
      s_wc[cc][col] = ok ? WT[(C + c0 + cc) * O + o0 + col] : 0.f;
    }
    __syncthreads();
#pragma unroll
    for (int cc = 0; cc < 8; ++cc) {
      const float4 xv = *(const float4*)&s_x[cc][tn];
      const float4 wn = *(const float4*)&s_wn[cc][to];
      const float4 wc = *(const float4*)&s_wc[cc][to];
      const float xa[4] = {xv.x, xv.y, xv.z, xv.w};
      const float na[4] = {wn.x, wn.y, wn.z, wn.w};
      const float ca[4] = {wc.x, wc.y, wc.z, wc.w};
#pragma unroll
      for (int i = 0; i < 4; ++i)
#pragma unroll
        for (int j = 0; j < 4; ++j) {
          accU[i][j] = fmaf(xa[i], na[j], accU[i][j]);
          accC[i][j] = fmaf(xa[i], ca[j], accC[i][j]);
        }
    }
    __syncthreads();
  }
#pragma unroll
  for (int i = 0; i < 4; ++i) {
    const size_t base2 = ((size_t)(b << 10) + n0 + tn + i) * O + o0 + to;
    *(float4*)&U[base2] = make_float4(accU[i][0], accU[i][1], accU[i][2], accU[i][3]);
    *(float4*)&Vd[base2] = make_float4(accC[i][0] - accU[i][0], accC[i][1] - accU[i][1],
                                       accC[i][2] - accU[i][2], accC[i][3] - accU[i][3]);
  }
}

// ---------------------------------------------------------------------------
// edge gather pass (XCD batch affinity: block bx serves batch bx&7).
// Grid 512 (atomic-tail-pinned); stats banked 8-ways by (bx&7).
// ---------------------------------------------------------------------------
template <int O>
__global__ __launch_bounds__(256) void edge_pass_kernel(
    const float* __restrict__ U, const float* __restrict__ Vd,
    const int* __restrict__ idxb, const float* __restrict__ g,
    float* __restrict__ stats, float* __restrict__ ysel) {
  constexpr int PSUB = 256 / O;
  __shared__ float s_red[256];
  const int t = threadIdx.x;
  const int o = t & (O - 1);
  const int psub = t / O;
  const bool usemax = g[o] >= 0.f;
  const int bsel = blockIdx.x & 7;            // batch == presumed XCD
  const int wb = blockIdx.x >> 3;             // 0..63 within batch
  float* st1 = stats + bsel * 256;            // banked partials
  float* st2 = stats + 2048 + bsel * 256;
  const float* ub = U + ((size_t)(bsel << 10)) * O;
  float ls1 = 0.f, ls2 = 0.f;
  for (int pl = wb * PSUB + psub; pl < NN; pl += 64 * PSUB) {
    const int p = (bsel << 10) + pl;
    int id[KNB];
#pragma unroll
    for (int k = 0; k < KNB; ++k) id[k] = idxb[p * KNB + k];
    const float vd = Vd[(size_t)p * O + o];
    float ymx = -3.4e38f, ymn = 3.4e38f;
#pragma unroll
    for (int k = 0; k < KNB; ++k) {
      const float y = ub[(size_t)id[k] * O + o] + vd;
      ymx = fmaxf(ymx, y);
      ymn = fminf(ymn, y);
      ls1 += y;
      ls2 = fmaf(y, y, ls2);
    }
    ysel[(size_t)p * O + o] = usemax ? ymx : ymn;
  }
  if (PSUB == 1) {
    atomicAdd(&st1[o], ls1);
    atomicAdd(&st2[o], ls2);
  } else {
    s_red[t] = ls1;
    __syncthreads();
    if (t < O) {
      float s = s_red[t];
#pragma unroll
      for (int p2 = 1; p2 < PSUB; ++p2) s += s_red[t + p2 * O];
      atomicAdd(&st1[t], s);
    }
    __syncthreads();
    s_red[t] = ls2;
    __syncthreads();
    if (t < O) {
      float s = s_red[t];
#pragma unroll
      for (int p2 = 1; p2 < PSUB; ++p2) s += s_red[t + p2 * O];
      atomicAdd(&st2[t], s);
    }
  }
}

// ---------------------------------------------------------------------------
// bn_apply (finalize inlined, sums 8 stats banks) + transpose; packed bf16
// write for conv1d MFMA. hout may be null (stage 4 MFMA path: dead store).
// ---------------------------------------------------------------------------
template <int O>
__global__ __launch_bounds__(256) void bn_apply_kernel(
    const float* __restrict__ ysel, const float* __restrict__ stats,
    const float* __restrict__ g, const float* __restrict__ bb,
    float* __restrict__ hout, unsigned short* __restrict__ hp, int coff) {
  constexpr int OT = O / 32;
  __shared__ float s_t[32][33];
  const int t = threadIdx.x;
  const int bx = blockIdx.x;
  const int b = bx / (32 * OT);
  const int r = bx % (32 * OT);
  const int n0 = (r / OT) * 32;
  const int o0 = (r % OT) * 32;
  const int col = t & 31, rowb = t >> 5;
  const int o = o0 + col;
  const float inv = 1.f / (8.f * 1024.f * 20.f);
  float sum1 = 0.f, sum2 = 0.f;
#pragma unroll
  for (int j = 0; j < 8; ++j) {
    sum1 += stats[j * 256 + o];
    sum2 += stats[2048 + j * 256 + o];
  }
  const float mean = sum1 * inv;
  const float var = sum2 * inv - mean * mean;
  const float sc = g[o] * rsqrtf(var + BNEPS);
  const float sh = bb[o] - mean * sc;
  const int c = coff + o;               // conv1d K index
#pragma unroll
  for (int rr = 0; rr < 4; ++rr) {
    const int nl = n0 + rowb + rr * 8;
    const float y = ysel[((size_t)(b << 10) + nl) * O + o];
    const float h = lrelu(fmaf(sc, y, sh));
    if (hout) s_t[rowb + rr * 8][col] = h;
    if (hp) {
      const int lane2 = (nl & 31) + ((c >> 3) & 1) * 32;
      hp[(((size_t)(b * 32 + (nl >> 5)) * 32 + (c >> 4)) * 64 + lane2) * 8 +
         (c & 7)] = f2b(h);
    }
  }
  if (hout) {
    __syncthreads();
#pragma unroll
    for (int rr = 0; rr < 4; ++rr) {
      const int ol = rowb + rr * 8;
      hout[(size_t)b * (512 * 1024) + (o0 + ol) * NN + n0 + col] = s_t[col][ol];
    }
  }
}

// ---------------------------------------------------------------------------
// conv1d via MFMA on packed fragments: Y5[b][o][n] = sum_c W5[o][c]*h[b][n][c]
// ---------------------------------------------------------------------------
__global__ __launch_bounds__(256) void conv1d_mfma_kernel(
    const unsigned short* __restrict__ hp,
    const unsigned short* __restrict__ w5p, float* __restrict__ Y5) {
  const int t = threadIdx.x, bx = blockIdx.x;
  const int b = bx >> 6;
  const int r = bx & 63;
  const int w = t >> 6, lane = t & 63;
  const int ot0 = (r >> 3) * 4 + (w & 1) * 2;
  const int nt0 = (r & 7) * 4 + (w >> 1) * 2;
  const unsigned short* a0p = w5p + (size_t)ot0 * 16384 + lane * 8;
  const unsigned short* a1p = a0p + 16384;
  const unsigned short* b0p = hp + (size_t)(b * 32 + nt0) * 16384 + lane * 8;
  const unsigned short* b1p = b0p + 16384;
  f32x16 acc00, acc01, acc10, acc11;
#pragma unroll
  for (int i = 0; i < 16; ++i) { acc00[i] = 0.f; acc01[i] = 0.f; acc10[i] = 0.f; acc11[i] = 0.f; }
#pragma unroll 2
  for (int kb = 0; kb < 32; ++kb) {
    const int off = kb * 512;
    const short8v a0 = *(const short8v*)(a0p + off);
    const short8v a1 = *(const short8v*)(a1p + off);
    const short8v b0 = *(const short8v*)(b0p + off);
    const short8v b1 = *(const short8v*)(b1p + off);
    acc00 = __builtin_amdgcn_mfma_f32_32x32x16_bf16(a0, b0, acc00, 0, 0, 0);
    acc01 = __builtin_amdgcn_mfma_f32_32x32x16_bf16(a0, b1, acc01, 0, 0, 0);
    acc10 = __builtin_amdgcn_mfma_f32_32x32x16_bf16(a1, b0, acc10, 0, 0, 0);
    acc11 = __builtin_amdgcn_mfma_f32_32x32x16_bf16(a1, b1, acc11, 0, 0, 0);
  }
  const int l31 = lane & 31, l5 = lane >> 5;
#pragma unroll
  for (int oi = 0; oi < 2; ++oi) {
#pragma unroll
    for (int nj = 0; nj < 2; ++nj) {
      const f32x16 a = (oi == 0) ? (nj == 0 ? acc00 : acc01)
                                 : (nj == 0 ? acc10 : acc11);
      const int ob = (ot0 + oi) * 32;
      const int nb = (nt0 + nj) * 32;
#pragma unroll
      for (int r16 = 0; r16 < 16; ++r16) {
        const int row = (r16 & 3) + 8 * (r16 >> 2) + 4 * l5;
        Y5[((size_t)(b << 10) + ob + row) * 1024 + nb + l31] = a[r16];
      }
    }
  }
}

// ---------------------------------------------------------------------------
// c1pool: one block per channel o; single HBM pass (rows staged in LDS).
// ---------------------------------------------------------------------------
__global__ __launch_bounds__(256) void c1pool_kernel(
    const float* __restrict__ Y5, const float* __restrict__ g,
    const float* __restrict__ bb, float* __restrict__ z) {
  __shared__ __align__(16) float s_y[8][1024];
  __shared__ float sr[256];
  __shared__ float s_par[2];
  const int o = blockIdx.x, t = threadIdx.x;
  float s1 = 0.f, s2 = 0.f;
#pragma unroll
  for (int b = 0; b < 8; ++b) {
    const float4 v = *(const float4*)&Y5[((size_t)((b << 10) + o)) * 1024 + t * 4];
    *(float4*)&s_y[b][t * 4] = v;
    s1 += v.x + v.y + v.z + v.w;
    s2 = fmaf(v.x, v.x, s2);
    s2 = fmaf(v.y, v.y, s2);
    s2 = fmaf(v.z, v.z, s2);
    s2 = fmaf(v.w, v.w, s2);
  }
  sr[t] = s1;
  __syncthreads();
  for (int s = 128; s > 0; s >>= 1) {
    if (t < s) sr[t] += sr[t + s];
    __syncthreads();
  }
  if (t == 0) s_par[0] = sr[0];
  __syncthreads();
  sr[t] = s2;
  __syncthreads();
  for (int s = 128; s > 0; s >>= 1) {
    if (t < s) sr[t] += sr[t + s];
    __syncthreads();
  }
  if (t == 0) {
    const float mean = s_par[0] * (1.f / 8192.f);
    const float var = sr[0] * (1.f / 8192.f) - mean * mean;
    const float sc = g[o] * rsqrtf(var + BNEPS);
    s_par[0] = sc;
    s_par[1] = bb[o] - mean * sc;
  }
  __syncthreads();
  const float sc = s_par[0], sh = s_par[1];
  const int lane = t & 63, w = t >> 6;
#pragma unroll
  for (int h = 0; h < 2; ++h) {
    const int b = w + h * 4;
    float mx = -3.4e38f, sm = 0.f;
#pragma unroll
    for (int j = 0; j < 4; ++j) {
      const float4 v = *(const float4*)&s_y[b][lane * 16 + j * 4];
      const float y0 = lrelu(fmaf(sc, v.x, sh));
      const float y1 = lrelu(fmaf(sc, v.y, sh));
      const float y2 = lrelu(fmaf(sc, v.z, sh));
      const float y3 = lrelu(fmaf(sc, v.w, sh));
      mx = fmaxf(fmaxf(fmaxf(mx, y0), fmaxf(y1, y2)), y3);
      sm += y0 + y1 + y2 + y3;
    }
#pragma unroll
    for (int off = 1; off < 64; off <<= 1) {
      mx = fmaxf(mx, __shfl_xor(mx, off, 64));
      sm += __shfl_xor(sm, off, 64);
    }
    if (lane == 0) {
      z[b * 2048 + o] = mx;
      z[b * 2048 + 1024 + o] = sm * (1.f / 1024.f);
    }
  }
}

// ---------------------------------------------------------------------------
// fallback f32 conv1d (used only if ws too small for MFMA buffers)
// ---------------------------------------------------------------------------
__global__ void bn_finalize_kernel(float* __restrict__ stats,
                                   const float* __restrict__ g,
                                   const float* __restrict__ bb, int cout,
                                   float inv_cnt) {
  const int o = blockIdx.x * 256 + threadIdx.x;
  if (o >= cout) return;
  const float mean = stats[o] * inv_cnt;
  const float var = stats[1024 + o] * inv_cnt - mean * mean;
  const float s = g[o] * rsqrtf(var + BNEPS);
  stats[2048 + o] = s;
  stats[3072 + o] = bb[o] - mean * s;
}

__global__ __launch_bounds__(256) void conv1d_gemm_kernel(
    const float* __restrict__ hcat, const float* __restrict__ WT5,
    float* __restrict__ stats, float* __restrict__ Y5) {
  __shared__ __align__(16) float s_w[8][64];
  __shared__ __align__(16) float s_h[8][64];
  __shared__ __align__(16) float s_red[64][16];
  const int t = threadIdx.x;
  const int bx = blockIdx.x;
  const int b = bx >> 8;
  const int o0 = ((bx >> 4) & 15) * 64;
  const int n0 = (bx & 15) * 64;
  const float* hb = hcat + (size_t)b * (512 * 1024);
  const int to = (t >> 4) * 4;
  const int tn = (t & 15) * 4;
  float acc[4][4] = {};
  for (int c0 = 0; c0 < 512; c0 += 8) {
    for (int i = t; i < 8 * 64; i += 256) {
      const int cc = i >> 6, col = i & 63;
      s_w[cc][col] = WT5[(c0 + cc) * 1024 + o0 + col];
      s_h[cc][col] = hb[(c0 + cc) * NN + n0 + col];
    }
    __syncthreads();
#pragma unroll
    for (int cc = 0; cc < 8; ++cc) {
      const float4 wv = *(const float4*)&s_w[cc][to];
      const float4 hv = *(const float4*)&s_h[cc][tn];
      const float wa[4] = {wv.x, wv.y, wv.z, wv.w};
      const float ha[4] = {hv.x, hv.y, hv.z, hv.w};
#pragma unroll
      for (int i = 0; i < 4; ++i)
#pragma unroll
        for (int j = 0; j < 4; ++j) acc[i][j] = fmaf(wa[i], ha[j], acc[i][j]);
    }
    __syncthreads();
  }
#pragma unroll
  for (int i = 0; i < 4; ++i) {
    *(float4*)&Y5[((size_t)(b << 10) + o0 + to + i) * NN + n0 + tn] =
        make_float4(acc[i][0], acc[i][1], acc[i][2], acc[i][3]);
  }
#pragma unroll
  for (int i = 0; i < 4; ++i)
    s_red[to + i][t & 15] = acc[i][0] + acc[i][1] + acc[i][2] + acc[i][3];
  __syncthreads();
  if (t < 64) {
    float s = 0.f;
#pragma unroll
    for (int g2 = 0; g2 < 16; ++g2) s += s_red[t][g2];
    atomicAdd(&stats[o0 + t], s);
  }
  __syncthreads();
#pragma unroll
  for (int i = 0; i < 4; ++i) {
    float s = 0.f;
#pragma unroll
    for (int j = 0; j < 4; ++j) s = fmaf(acc[i][j], acc[i][j], s);
    s_red[to + i][t & 15] = s;
  }
  __syncthreads();
  if (t < 64) {
    float s = 0.f;
#pragma unroll
    for (int g2 = 0; g2 < 16; ++g2) s += s_red[t][g2];
    atomicAdd(&stats[1024 + o0 + t], s);
  }
}

__global__ __launch_bounds__(256) void pool_kernel(
    const float* __restrict__ Y5, const float* __restrict__ stats,
    float* __restrict__ z) {
  const int t = threadIdx.x;
  const int lane = t & 63;
  const int bx = blockIdx.x;
  const int b = bx >> 8;
  const int o = (bx & 255) * 4 + (t >> 6);
  const float sc = stats[2048 + o], sh = stats[3072 + o];
  const float* yr = Y5 + ((size_t)(b << 10) + o) * NN;
  float mx = -3.4e38f, sm = 0.f;
#pragma unroll
  for (int j = 0; j < 16; ++j) {
    const float y = lrelu(fmaf(sc, yr[j * 64 + lane], sh));
    mx = fmaxf(mx, y);
    sm += y;
  }
  for (int off = 32; off > 0; off >>= 1) {
    mx = fmaxf(mx, __shfl_down(mx, off, 64));
    sm += __shfl_down(sm, off, 64);
  }
  if (lane == 0) {
    z[b * 2048 + o] = mx;
    z[b * 2048 + 1024 + o] = sm * (1.f / 1024.f);
  }
}

// ---------------------------------------------------------------------------
// MLP layer with batch-of-8 BN + lrelu fused. W/bias read RAW from inputs.
// ---------------------------------------------------------------------------
__global__ __launch_bounds__(256) void mlp_kernel(
    const float* __restrict__ zin, const void* __restrict__ W,
    const void* __restrict__ bias, const int* __restrict__ flags, int wfl,
    int bfl, const float* __restrict__ g, const float* __restrict__ bb,
    int kin, float* __restrict__ out, int O) {
  __shared__ float s_red[256];
  __shared__ float s_y[8];
  const int t = threadIdx.x;
  const int o = blockIdx.x;
  const int fw = flags[wfl];
  float acc[8];
#pragma unroll
  for (int b = 0; b < 8; ++b) acc[b] = 0.f;
  for (int c = t; c < kin; c += 256) {
    const float w = load_in(W, fw, o * kin + c);
#pragma unroll
    for (int b = 0; b < 8; ++b) acc[b] = fmaf(w, zin[b * kin + c], acc[b]);
  }
  for (int b = 0; b < 8; ++b) {
    s_red[t] = acc[b];
    __syncthreads();
    for (int s = 128; s > 0; s >>= 1) {
      if (t < s) s_red[t] += s_red[t + s];
      __syncthreads();
    }
    if (t == 0)
      s_y[b] = s_red[0] + (bias ? load_in(bias, flags[bfl], o) : 0.f);
    __syncthreads();
  }
  if (t == 0) {
    float m = 0.f;
    for (int b = 0; b < 8; ++b) m += s_y[b];
    m *= 0.125f;
    float v = 0.f;
    for (int b = 0; b < 8; ++b) { const float d = s_y[b] - m; v = fmaf(d, d, v); }
    v *= 0.125f;
    const float s = g[o] * rsqrtf(v + BNEPS);
    const float sh = bb[o] - m * s;
    for (int b = 0; b < 8; ++b) out[b * O + o] = lrelu(fmaf(s, s_y[b], sh));
  }
}

// final: out = z2 @ Wl3^T + bl3 (raw reads); output dtype from flags.
__global__ void final_kernel(const float* __restrict__ z2,
                             const void* __restrict__ Wl3,
                             const void* __restrict__ bl3,
                             const int* __restrict__ flags, void* out) {
  const int j = blockIdx.x * 256 + threadIdx.x;
  if (j >= 320) return;
  int anyf32 = 0, anybf = 0;
  for (int i = 0; i < NIN; ++i) {
    const int fl = flags[i];
    if (fl == 0) anyf32 = 1;
    if (fl == 1) anybf = 1;
  }
  const int bf16out = (anybf && !anyf32) ? 1 : 0;
  const int fw = flags[9], fb = flags[10];
  const int b = j / 40, o = j - b * 40;
  float s = load_in(bl3, fb, o);
  for (int c = 0; c < 256; ++c)
    s = fmaf(z2[b * 256 + c], load_in(Wl3, fw, o * 256 + c), s);
  if (bf16out) ((__hip_bfloat16*)out)[j] = __float2bfloat16(s);
  else ((float*)out)[j] = s;
}

// ---------------------------------------------------------------------------
template <int C, int O>
static void run_stage(float* wsf, const float* xbase, int bstr, int widx,
                      int gidx, int bidx, int stat, float* hout,
                      unsigned short* hp, int coff, hipStream_t stream) {
  int* idxb = reinterpret_cast<int*>(wsf + IDXo);
  float* U = wsf + U_OFF;
  float* Vd = wsf + VD_OFF;
  float* ysel = wsf + YS_OFF;
  float* stats = wsf + STATSo + stat * 4096;
  tg_kernel<C, O><<<512 + BB * 16 * (O / 64), 256, 0, stream>>>(
      xbase, bstr, wsf + widx, U, Vd, idxb);
  edge_pass_kernel<O><<<512, 256, 0, stream>>>(U, Vd, idxb, wsf + gidx, stats,
                                               ysel);
  bn_apply_kernel<O><<<BB * 32 * (O / 32), 256, 0, stream>>>(
      ysel, stats, wsf + gidx, wsf + bidx, hout, hp, coff);
}

extern "C" void kernel_launch(void* const* d_in, const int* in_sizes, int n_in,
                              void* d_out, int out_size, void* d_ws,
                              size_t ws_size, hipStream_t stream) {
  (void)in_sizes; (void)n_in; (void)out_size;
  float* wsf = reinterpret_cast<float*>(d_ws);
  int* flags = reinterpret_cast<int*>(wsf + FLAGSo);
  float* hcat = wsf + HCATo;
  const bool mf = ws_size >= WS_NEED_MFMA;
  unsigned short* hp = mf ? reinterpret_cast<unsigned short*>(wsf + HBFo) : nullptr;
  unsigned short* w5p = reinterpret_cast<unsigned short*>(wsf + W5BFo);

  Ptrs ptrs;
  for (int i = 0; i < NIN; ++i) ptrs.p[i] = d_in[i];

  detect_kernel<<<NIN, 64, 0, stream>>>(ptrs, flags);
  const int nmain = mf ? NMAIN_MF : NCONV;
  convert_kernel<<<nmain + 80 + 256, 256, 0, stream>>>(ptrs, flags, wsf,
                                                       mf ? 1 : 0, nmain);

  run_stage<3, 64>(wsf, wsf + XIN, 3 * NN, WT1, G1, B1o, 0, hcat, hp, 0,
                   stream);
  run_stage<64, 64>(wsf, hcat, 512 * NN, WT2, G2, B2o, 1, hcat + 64 * NN, hp,
                    64, stream);
  run_stage<64, 128>(wsf, hcat + 64 * NN, 512 * NN, WT3, G3, B3o, 2,
                     hcat + 128 * NN, hp, 128, stream);
  // stage 4: f32 hout is dead in the MFMA path (only packed hp consumed)
  run_stage<128, 256>(wsf, hcat + 128 * NN, 512 * NN, WT4, G4, B4o, 3,
                      mf ? nullptr : (hcat + 256 * NN), hp, 256, stream);

  // conv1d 512->1024 + BN + pool
  float* Y5 = wsf + Y5_OFF;
  float* st5 = wsf + STATSo + 4 * 4096;
  if (mf) {
    conv1d_mfma_kernel<<<512, 256, 0, stream>>>(hp, w5p, Y5);
    c1pool_kernel<<<1024, 256, 0, stream>>>(Y5, wsf + G5, wsf + B5o,
                                            wsf + Z2048o);
  } else {
    conv1d_gemm_kernel<<<2048, 256, 0, stream>>>(hcat, wsf + WT5, st5, Y5);
    bn_finalize_kernel<<<4, 256, 0, stream>>>(st5, wsf + G5, wsf + B5o, 1024,
                                              1.f / 8192.f);
    pool_kernel<<<BB * 256, 256, 0, stream>>>(Y5, st5, wsf + Z2048o);
  }

  // MLP head (raw W/bias reads)
  mlp_kernel<<<512, 256, 0, stream>>>(wsf + Z2048o, d_in[6], nullptr, flags,
      6, 0, wsf + G6, wsf + B6o, 2048, wsf + Z1o, 512);
  mlp_kernel<<<256, 256, 0, stream>>>(wsf + Z1o, d_in[7], d_in[8], flags,
      7, 8, wsf + G7, wsf + B7o, 512, wsf + Z2o, 256);
  final_kernel<<<2, 256, 0, stream>>>(wsf + Z2o, d_in[9], d_in[10],
      flags, d_out);
}

// Round 17
// 414.211 us; speedup vs baseline: 1.0853x; 1.0442x over previous
//
#include <hip/hip_runtime.h>
#include <hip/hip_bf16.h>
#include <cstdint>

// ---------------------------------------------------------------------------
// DGCNN forward on MI355X. Math f32; conv1d via bf16 MFMA on packed
// fragment layouts; kNN via FUSED dist+topk.
// R30: 512-thread fused blocks (8 waves x 2 rows) -- the confound-free
// version of R28. Evidence ledger for fused tg stuck at 85.5us: bank
// conflicts 4.23M->0 null (R27); 2x blocks negative (R28: staging work
// doubled); ballot-interleave null (R29). Untested: waves/SIMD 2->4 with
// staging UNCHANGED (same 512 blocks, more waves per block). Per-wave topk
// tail halves; per-thread FMA halves; VGPR drops. gemm_uv retiled for 512
// threads (2x4 micro-tile; same ascending-cc FMA order -> bit-identical
// U/Vd). All per-(row,col) FMA orders unchanged -> absmax canary
// 0.02050781. Kept: conflict-free col ownership {lane+64j}, interleaved
// search, banked stats atomics + 8-bank bn sum, edge XCD batch affinity,
// convert compaction + raw MLP reads, c1pool single-pass, stage-4 hout
// skip. If tg stays ~85: fused floor is intra-wave serial -> revert R26.
// ---------------------------------------------------------------------------

static constexpr int BB  = 8;
static constexpr int NN  = 1024;
static constexpr int KNB = 20;
static constexpr float BNEPS = 1e-5f;

static constexpr int NIN = 25;

__constant__ int c_cum[NIN + 1] = {
    0, 24576, 24960, 33152, 49536, 115072, 639360,
    1687936, 1819008, 1819264, 1829504, 1829544, 1829608, 1829672, 1829736,
    1829800, 1829928, 1830056, 1830312, 1830568, 1831592, 1832616, 1833128,
    1833640, 1833896, 1834152};
__constant__ int c_trO[NIN] = {0, 64, 64, 128, 256, 1024, 0, 0, 0, 0, 0,
                               0, 0, 0, 0, 0, 0, 0, 0, 0, 0, 0, 0, 0, 0};
__constant__ int c_trI[NIN] = {0, 6, 128, 128, 256, 512, 0, 0, 0, 0, 0,
                               0, 0, 0, 0, 0, 0, 0, 0, 0, 0, 0, 0, 0, 0};

enum : int {
  XIN = 0, WT1 = 24576, WT2 = 24960, WT3 = 33152, WT4 = 49536, WT5 = 115072,
  WL1 = 639360, WL2 = 1687936, BL2o = 1819008, WL3 = 1819264, BL3o = 1829504,
  G1 = 1829544, B1o = 1829608, G2 = 1829672, B2o = 1829736,
  G3 = 1829800, B3o = 1829928, G4 = 1830056, B4o = 1830312,
  G5 = 1830568, B5o = 1831592, G6 = 1832616, B6o = 1833128,
  G7 = 1833640, B7o = 1833896,
  IDXo = 1842432,       // 163840 i32
  HCATo = 2006272,      // 8*512*1024 f
  STATSo = 6200576,     // 5 layers * 4096 f (stages 0-3: 8-banked partials)
  Z2048o = 6237440,     // 8*2048 f
  Z1o = 6253824,        // 8*512 f
  Z2o = 6257920,        // 8*256 f
  FLAGSo = 6259968,     // 32 i32
  DISTo = 6260736,      // window (U/Vd/ysel; D not materialized)
  HBFo  = 14649344,     // packed bf16 h: 8*1024*512 shorts (2M float slots)
  W5BFo = 16746496      // packed bf16 w5: 512K shorts -> ends 17008640
};
static constexpr int TOTAL_IN = 1834152;
static constexpr int NCONV = (TOTAL_IN + 255) / 256;   // full-copy blocks (!mf)
static constexpr int NMAIN_ELEMS = 115072 + 4608;      // 119680
static constexpr int NMAIN_MF = (NMAIN_ELEMS + 255) / 256;  // 468 blocks
static constexpr int U_OFF   = DISTo + 0;
static constexpr int VD_OFF  = DISTo + 2097152;
static constexpr int YS_OFF  = DISTo + 4194304;
static constexpr int Y5_OFF  = DISTo + 0;
static constexpr size_t WS_NEED_MFMA = (size_t)17008640 * 4;  // ~68 MB

struct Ptrs { const void* p[NIN]; };

typedef short short8v __attribute__((ext_vector_type(8)));
typedef float f32x16 __attribute__((ext_vector_type(16)));

__device__ __forceinline__ float lrelu(float y) { return (y < 0.f) ? 0.2f * y : y; }
__device__ __forceinline__ unsigned short f2b(float f) {
  unsigned u = __float_as_uint(f);
  unsigned r = (u + 0x7FFFu + ((u >> 16) & 1u)) >> 16;   // RNE
  return (unsigned short)r;
}
// sortable key: monotone map float -> u32 (larger float -> larger key)
__device__ __forceinline__ unsigned f2s(float f) {
  const unsigned s = __float_as_uint(f);
  return s ^ ((unsigned)((int)s >> 31) | 0x80000000u);
}
__device__ __forceinline__ float load_in(const void* p, int fl, int idx) {
  if (fl == 2) return 0.f;
  if (fl == 1) {
    const unsigned short u = ((const unsigned short*)p)[idx];
    return __uint_as_float(((unsigned)u) << 16);
  }
  return ((const float*)p)[idx];
}
__device__ __forceinline__ int mbcnt64(unsigned long long m) {
  return __builtin_amdgcn_mbcnt_hi((unsigned)(m >> 32),
                                   __builtin_amdgcn_mbcnt_lo((unsigned)m, 0));
}

// ---------------------------------------------------------------------------
// dtype detection
// ---------------------------------------------------------------------------
__global__ void detect_kernel(Ptrs ptrs, int* __restrict__ flags) {
  const int i = blockIdx.x;
  const unsigned* p = (const unsigned*)ptrs.p[i];
  const int n = c_cum[i + 1] - c_cum[i];
  int words = n >> 1; if (words > 64) words = 64;
  const int t = threadIdx.x;
  unsigned w = (t < words) ? p[t] : 0u;
  bool nz = (w != 0u);
  unsigned e = (w >> 7) & 0xFFu;
  bool pl = nz && (e >= 96u) && (e <= 140u);
  unsigned long long mnz = __ballot(nz);
  unsigned long long mpl = __ballot(pl);
  if (t == 0) {
    int cnz = __popcll(mnz), cpl = __popcll(mpl);
    flags[i] = (cnz == 0) ? 2 : ((2 * cpl > words) ? 1 : 0);
  }
}

// ---------------------------------------------------------------------------
// convert: main blocks convert+transpose inputs; tail1 zeroes stats;
// tail2 packs w5 (raw input -> MFMA A-fragment bf16) if do_w5.
// ---------------------------------------------------------------------------
__global__ void convert_kernel(Ptrs ptrs, const int* __restrict__ flags,
                               float* __restrict__ ws, int do_w5, int nmain) {
  const int bx = blockIdx.x;
  const int t = threadIdx.x;
  if (bx >= nmain + 80) {            // tail2: w5 packing
    if (!do_w5) return;
    const int g = (bx - nmain - 80) * 256 + t;   // 0..65535
    const int lane = g & 63;
    const int kb = (g >> 6) & 31;
    const int ot = g >> 11;
    const int o = ot * 32 + (lane & 31);
    const int k0 = kb * 16 + (lane >> 5) * 8;
    const void* w5raw = ptrs.p[5];
    const int fl = flags[5];
    unsigned u[4];
#pragma unroll
    for (int h = 0; h < 4; ++h) {
      const unsigned short lo = f2b(load_in(w5raw, fl, o * 512 + k0 + 2 * h));
      const unsigned short hi = f2b(load_in(w5raw, fl, o * 512 + k0 + 2 * h + 1));
      u[h] = (unsigned)lo | ((unsigned)hi << 16);
    }
    unsigned short* w5p = (unsigned short*)(ws + W5BFo);
    *(uint4*)&w5p[(size_t)g * 8] = make_uint4(u[0], u[1], u[2], u[3]);
    return;
  }
  if (bx >= nmain) {                 // tail1: zero stats
    const int z = (bx - nmain) * 256 + t;
    if (z < 20480) ws[STATSo + z] = 0.f;
    return;
  }
  int e;
  if (do_w5) {                       // compact map
    const int e2 = bx * 256 + t;
    if (e2 >= NMAIN_ELEMS) return;
    e = (e2 < 115072) ? e2 : (e2 - 115072 + 1829544);
  } else {
    e = bx * 256 + t;
    if (e >= TOTAL_IN) return;
  }
  int i = 0;
  while (e >= c_cum[i + 1]) ++i;
  const int el = e - c_cum[i];
  int src;
  const int O = c_trO[i];
  if (O > 0) {
    const int I = c_trI[i];
    const int o = el % O, ii = el / O;
    src = o * I + ii;
  } else src = el;
  ws[e] = load_in(ptrs.p[i], flags[i], src);
}

// ---------------------------------------------------------------------------
// merged FUSED dist+topk (blocks 0..511) + gemm_uv (blocks 512..).
// 512 threads/block. Fused: 16 rows/block, 8 waves x 2 rows; lane owns
// cols {lane+64j} (bank = lane%32 -> free). gemm_uv retiled 2x4/thread.
// ---------------------------------------------------------------------------
template <int C, int O>
__global__ __launch_bounds__(512) void tg_kernel(
    const float* __restrict__ xbase, int bstr, const float* __restrict__ WT,
    float* __restrict__ U, float* __restrict__ Vd, int* __restrict__ idxb) {
  constexpr int OT = O / 64;
  __shared__ __align__(16) float s_mem[8 * 1024 + 128 + 1024];
  const int t = threadIdx.x;
  if (blockIdx.x < 512) {
    float (*s_b)[1024] = (float(*)[1024])s_mem;
    float (*s_a)[8] = (float(*)[8])(s_mem + 8192);
    float* s_xx = s_mem + 8192 + 128;
    const int b = blockIdx.x & 7;          // batch (XCD-affine)
    const int rg = blockIdx.x >> 3;        // 0..63
    const int r0 = rg * 16;
    const float* xb = xbase + (size_t)b * bstr;
    const int wv = t >> 6, lane = t & 63;  // wv 0..7
    float acc[2][16] = {};
    float xxa[2] = {0.f, 0.f};
    for (int c0 = 0; c0 < C; c0 += 8) {
      const int kc = (C - c0 < 8) ? (C - c0) : 8;
      __syncthreads();
      for (int i = t; i < 2048; i += 512) {          // B: [8][1024] (zero-pad)
        const int cc = i >> 8, col4 = (i & 255) * 4;
        float4 v = make_float4(0.f, 0.f, 0.f, 0.f);
        if (cc < kc) v = *(const float4*)&xb[(c0 + cc) * NN + col4];
        *(float4*)&s_b[cc][col4] = v;
      }
      if (t < 128) {                                  // A: [16][8]
        const int rr = t >> 3, cc = t & 7;
        s_a[rr][cc] = (cc < kc) ? xb[(c0 + cc) * NN + r0 + rr] : 0.f;
      }
      __syncthreads();
#pragma unroll
      for (int cc = 0; cc < 8; ++cc) {
        float a2[2];
#pragma unroll
        for (int ri = 0; ri < 2; ++ri) a2[ri] = s_a[wv * 2 + ri][cc];
        float bv[16];
#pragma unroll
        for (int j = 0; j < 16; ++j) bv[j] = s_b[cc][lane + 64 * j];
#pragma unroll
        for (int ri = 0; ri < 2; ++ri)
#pragma unroll
          for (int j = 0; j < 16; ++j)
            acc[ri][j] = fmaf(a2[ri], bv[j], acc[ri][j]);
#pragma unroll
        for (int q = 0; q < 2; ++q) {                // col-norm partials
          const float v = s_b[cc][q * 512 + t];
          xxa[q] = fmaf(v, v, xxa[q]);
        }
      }
    }
    __syncthreads();
#pragma unroll
    for (int q = 0; q < 2; ++q) s_xx[q * 512 + t] = xxa[q];
    __syncthreads();
    float xm[16];
#pragma unroll
    for (int j = 0; j < 16; ++j) xm[j] = s_xx[lane + 64 * j];
    unsigned long long* scw = (unsigned long long*)s_mem + wv * 128;
    // ---- keys for both rows (acc dead after -> regs reused) ----
    unsigned k16a[2][16];
    unsigned lmax2[2];
#pragma unroll
    for (int ri = 0; ri < 2; ++ri) {
      const float xxn = s_xx[r0 + wv * 2 + ri];
      unsigned lm = 0u;
#pragma unroll
      for (int j = 0; j < 16; ++j) {
        k16a[ri][j] = f2s(2.f * acc[ri][j] - xxn - xm[j]);
        lm = (k16a[ri][j] > lm) ? k16a[ri][j] : lm;
      }
      lmax2[ri] = lm;
    }
    // ---- interleaved binary search: 2 independent ballots per iter ----
    unsigned T2[2] = {0u, 0u};
    for (int bb2 = 31; bb2 >= 0; --bb2) {
#pragma unroll
      for (int ri = 0; ri < 2; ++ri) {
        const unsigned cand = T2[ri] | (1u << bb2);
        if (__popcll(__ballot(lmax2[ri] >= cand)) >= KNB) T2[ri] = cand;
      }
    }
    // ---- per-row tails (compact / rank / scatter) ----
#pragma unroll
    for (int ri = 0; ri < 2; ++ri) {     // UNROLLED: static indices (rule #20)
      const int rowg = (b << 10) + r0 + wv * 2 + ri;
      const unsigned T = T2[ri];
      int cnt = 0;
#pragma unroll
      for (int j = 0; j < 16; ++j) cnt += (k16a[ri][j] >= T) ? 1 : 0;
      int n_c = 0, off = 0;
#pragma unroll
      for (int bb2 = 0; bb2 < 5; ++bb2) {
        const unsigned long long m = __ballot((cnt >> bb2) & 1);
        n_c += __popcll(m) << bb2;
        off += mbcnt64(m) << bb2;
      }
      if (n_c <= 128) {
#pragma unroll
        for (int j = 0; j < 16; ++j)
          if (k16a[ri][j] >= T) {
            const int ci = lane + 64 * j;
            scw[off] = (((unsigned long long)k16a[ri][j]) << 32) |
                       (unsigned long long)(0xFFFFFFFFu ^ (unsigned)ci);
            ++off;
          }
        if (n_c <= 64) {
          unsigned long long mye = 0ULL;
          if (lane < n_c) mye = scw[lane];
          int rank = 0;
          for (int j = 0; j < n_c; ++j) {
            const unsigned eh =
                (unsigned)__builtin_amdgcn_readlane((int)(mye >> 32), j);
            const unsigned el =
                (unsigned)__builtin_amdgcn_readlane((int)(mye & 0xFFFFFFFFu), j);
            const unsigned long long ej = (((unsigned long long)eh) << 32) | el;
            rank += (ej > mye) ? 1 : 0;
          }
          if (lane < n_c && rank < KNB)
            idxb[rowg * KNB + rank] =
                (int)(0xFFFFFFFFu ^ (unsigned)(mye & 0xFFFFFFFFu));
        } else {
          const unsigned long long mye = (lane < n_c) ? scw[lane] : 0ULL;
          const unsigned long long mye2 =
              (64 + lane < n_c) ? scw[64 + lane] : 0ULL;
          int r1 = 0, r2 = 0;
          for (int j = 0; j < n_c; ++j) {
            const unsigned long long ej = scw[j];   // broadcast read
            r1 += (ej > mye) ? 1 : 0;
            r2 += (ej > mye2) ? 1 : 0;
          }
          if (lane < n_c && r1 < KNB)
            idxb[rowg * KNB + r1] = (int)(0xFFFFFFFFu ^ (unsigned)mye);
          if (64 + lane < n_c && r2 < KNB)
            idxb[rowg * KNB + r2] = (int)(0xFFFFFFFFu ^ (unsigned)mye2);
        }
      } else {
        // ---- composite-u64 extraction fallback (exact; ~never) ----
        unsigned long long q[4] = {0ULL, 0ULL, 0ULL, 0ULL};
        unsigned emit = 0;
#pragma unroll
        for (int j = 0; j < 16; ++j) {
          const int ci = lane + 64 * j;
          const unsigned long long c =
              (((unsigned long long)k16a[ri][j]) << 32) |
              (unsigned long long)(0xFFFFFFFFu ^ (unsigned)ci);
          if (c > q[3]) {
            q[3] = c;
            if (q[3] > q[2]) { auto tv = q[2]; q[2] = q[3]; q[3] = tv; }
            if (q[2] > q[1]) { auto tv = q[1]; q[1] = q[2]; q[2] = tv; }
            if (q[1] > q[0]) { auto tv = q[0]; q[0] = q[1]; q[1] = tv; }
          }
        }
        for (int kk = 0; kk < KNB; ++kk) {
          unsigned long long best = q[0];
          for (int o2 = 1; o2 < 64; o2 <<= 1) {
            const unsigned long long p =
                (unsigned long long)__shfl_xor((long long)best, o2, 64);
            best = (p > best) ? p : best;
          }
          if (lane == 0)
            idxb[rowg * KNB + kk] = (int)(0xFFFFFFFFu ^ (unsigned)best);
          if (q[0] == best) {           // unique owner (idx in composite)
            const int ci = (int)(0xFFFFFFFFu ^ (unsigned)best);
            const int j = (ci - lane) >> 6;
            emit |= 1u << j;
            q[0] = q[1]; q[1] = q[2]; q[2] = q[3]; q[3] = 0ULL;
            if (q[0] == 0ULL && __popc(emit) < 16) {
              for (int j2 = 0; j2 < 16; ++j2)
                if (!((emit >> j2) & 1u)) {
                  const int ci2 = lane + 64 * j2;
                  const unsigned long long c2 =
                      (((unsigned long long)k16a[ri][j2]) << 32) |
                      (unsigned long long)(0xFFFFFFFFu ^ (unsigned)ci2);
                  if (c2 > q[3]) {
                    q[3] = c2;
                    if (q[3] > q[2]) { auto tv = q[2]; q[2] = q[3]; q[3] = tv; }
                    if (q[2] > q[1]) { auto tv = q[1]; q[1] = q[2]; q[2] = tv; }
                    if (q[1] > q[0]) { auto tv = q[0]; q[0] = q[1]; q[1] = tv; }
                  }
                }
            }
          }
        }
      }
    }
    return;
  }
  // ---- gemm_uv part (512 threads: 2x4 micro-tile; LDS aliased) ----
  float (*s_x)[64] = (float(*)[64])(s_mem);
  float (*s_wn)[64] = (float(*)[64])(s_mem + 512);
  float (*s_wc)[64] = (float(*)[64])(s_mem + 1024);
  const int bx = blockIdx.x - 512;
  const int b = bx / (16 * OT);
  const int r = bx % (16 * OT);
  const int n0 = (r / OT) * 64;
  const int o0 = (r % OT) * 64;
  const float* xb = xbase + (size_t)b * bstr;
  const int tn = (t >> 4) * 2;          // 0,2,..,62
  const int to = (t & 15) * 4;          // 0,4,..,60
  float accU[2][4] = {}, accC[2][4] = {};
  for (int c0 = 0; c0 < C; c0 += 8) {
    const int kc = (C - c0 < 8) ? (C - c0) : 8;
    {
      const int i = t;                  // one element per thread covers [8][64]
      const int cc = i >> 6, col = i & 63;
      const bool ok = cc < kc;
      s_x[cc][col]  = ok ? xb[(c0 + cc) * NN + n0 + col] : 0.f;
      s_wn[cc][col] = ok ? WT[(c0 + cc) * O + o0 + col] : 0.f;
      s_wc[cc][col] = ok ? WT[(C + c0 + cc) * O + o0 + col] : 0.f;
    }
    __syncthreads();
#pragma unroll
    for (int cc = 0; cc < 8; ++cc) {
      const float xa[2] = {s_x[cc][tn], s_x[cc][tn + 1]};
      const float4 wn = *(const float4*)&s_wn[cc][to];
      const float4 wc = *(const float4*)&s_wc[cc][to];
      const float na[4] = {wn.x, wn.y, wn.z, wn.w};
      const float ca[4] = {wc.x, wc.y, wc.z, wc.w};
#pragma unroll
      for (int i = 0; i < 2; ++i)
#pragma unroll
        for (int j = 0; j < 4; ++j) {
          accU[i][j] = fmaf(xa[i], na[j], accU[i][j]);
          accC[i][j] = fmaf(xa[i], ca[j], accC[i][j]);
        }
    }
    __syncthreads();
  }
#pragma unroll
  for (int i = 0; i < 2; ++i) {
    const size_t base2 = ((size_t)(b << 10) + n0 + tn + i) * O + o0 + to;
    *(float4*)&U[base2] = make_float4(accU[i][0], accU[i][1], accU[i][2], accU[i][3]);
    *(float4*)&Vd[base2] = make_float4(accC[i][0] - accU[i][0], accC[i][1] - accU[i][1],
                                       accC[i][2] - accU[i][2], accC[i][3] - accU[i][3]);
  }
}

// ---------------------------------------------------------------------------
// edge gather pass (XCD batch affinity: block bx serves batch bx&7).
// Grid 512 (atomic-tail-pinned); stats banked 8-ways by (bx&7).
// ---------------------------------------------------------------------------
template <int O>
__global__ __launch_bounds__(256) void edge_pass_kernel(
    const float* __restrict__ U, const float* __restrict__ Vd,
    const int* __restrict__ idxb, const float* __restrict__ g,
    float* __restrict__ stats, float* __restrict__ ysel) {
  constexpr int PSUB = 256 / O;
  __shared__ float s_red[256];
  const int t = threadIdx.x;
  const int o = t & (O - 1);
  const int psub = t / O;
  const bool usemax = g[o] >= 0.f;
  const int bsel = blockIdx.x & 7;            // batch == presumed XCD
  const int wb = blockIdx.x >> 3;             // 0..63 within batch
  float* st1 = stats + bsel * 256;            // banked partials
  float* st2 = stats + 2048 + bsel * 256;
  const float* ub = U + ((size_t)(bsel << 10)) * O;
  float ls1 = 0.f, ls2 = 0.f;
  for (int pl = wb * PSUB + psub; pl < NN; pl += 64 * PSUB) {
    const int p = (bsel << 10) + pl;
    int id[KNB];
#pragma unroll
    for (int k = 0; k < KNB; ++k) id[k] = idxb[p * KNB + k];
    const float vd = Vd[(size_t)p * O + o];
    float ymx = -3.4e38f, ymn = 3.4e38f;
#pragma unroll
    for (int k = 0; k < KNB; ++k) {
      const float y = ub[(size_t)id[k] * O + o] + vd;
      ymx = fmaxf(ymx, y);
      ymn = fminf(ymn, y);
      ls1 += y;
      ls2 = fmaf(y, y, ls2);
    }
    ysel[(size_t)p * O + o] = usemax ? ymx : ymn;
  }
  if (PSUB == 1) {
    atomicAdd(&st1[o], ls1);
    atomicAdd(&st2[o], ls2);
  } else {
    s_red[t] = ls1;
    __syncthreads();
    if (t < O) {
      float s = s_red[t];
#pragma unroll
      for (int p2 = 1; p2 < PSUB; ++p2) s += s_red[t + p2 * O];
      atomicAdd(&st1[t], s);
    }
    __syncthreads();
    s_red[t] = ls2;
    __syncthreads();
    if (t < O) {
      float s = s_red[t];
#pragma unroll
      for (int p2 = 1; p2 < PSUB; ++p2) s += s_red[t + p2 * O];
      atomicAdd(&st2[t], s);
    }
  }
}

// ---------------------------------------------------------------------------
// bn_apply (finalize inlined, sums 8 stats banks) + transpose; packed bf16
// write for conv1d MFMA. hout may be null (stage 4 MFMA path: dead store).
// ---------------------------------------------------------------------------
template <int O>
__global__ __launch_bounds__(256) void bn_apply_kernel(
    const float* __restrict__ ysel, const float* __restrict__ stats,
    const float* __restrict__ g, const float* __restrict__ bb,
    float* __restrict__ hout, unsigned short* __restrict__ hp, int coff) {
  constexpr int OT = O / 32;
  __shared__ float s_t[32][33];
  const int t = threadIdx.x;
  const int bx = blockIdx.x;
  const int b = bx / (32 * OT);
  const int r = bx % (32 * OT);
  const int n0 = (r / OT) * 32;
  const int o0 = (r % OT) * 32;
  const int col = t & 31, rowb = t >> 5;
  const int o = o0 + col;
  const float inv = 1.f / (8.f * 1024.f * 20.f);
  float sum1 = 0.f, sum2 = 0.f;
#pragma unroll
  for (int j = 0; j < 8; ++j) {
    sum1 += stats[j * 256 + o];
    sum2 += stats[2048 + j * 256 + o];
  }
  const float mean = sum1 * inv;
  const float var = sum2 * inv - mean * mean;
  const float sc = g[o] * rsqrtf(var + BNEPS);
  const float sh = bb[o] - mean * sc;
  const int c = coff + o;               // conv1d K index
#pragma unroll
  for (int rr = 0; rr < 4; ++rr) {
    const int nl = n0 + rowb + rr * 8;
    const float y = ysel[((size_t)(b << 10) + nl) * O + o];
    const float h = lrelu(fmaf(sc, y, sh));
    if (hout) s_t[rowb + rr * 8][col] = h;
    if (hp) {
      const int lane2 = (nl & 31) + ((c >> 3) & 1) * 32;
      hp[(((size_t)(b * 32 + (nl >> 5)) * 32 + (c >> 4)) * 64 + lane2) * 8 +
         (c & 7)] = f2b(h);
    }
  }
  if (hout) {
    __syncthreads();
#pragma unroll
    for (int rr = 0; rr < 4; ++rr) {
      const int ol = rowb + rr * 8;
      hout[(size_t)b * (512 * 1024) + (o0 + ol) * NN + n0 + col] = s_t[col][ol];
    }
  }
}

// ---------------------------------------------------------------------------
// conv1d via MFMA on packed fragments: Y5[b][o][n] = sum_c W5[o][c]*h[b][n][c]
// ---------------------------------------------------------------------------
__global__ __launch_bounds__(256) void conv1d_mfma_kernel(
    const unsigned short* __restrict__ hp,
    const unsigned short* __restrict__ w5p, float* __restrict__ Y5) {
  const int t = threadIdx.x, bx = blockIdx.x;
  const int b = bx >> 6;
  const int r = bx & 63;
  const int w = t >> 6, lane = t & 63;
  const int ot0 = (r >> 3) * 4 + (w & 1) * 2;
  const int nt0 = (r & 7) * 4 + (w >> 1) * 2;
  const unsigned short* a0p = w5p + (size_t)ot0 * 16384 + lane * 8;
  const unsigned short* a1p = a0p + 16384;
  const unsigned short* b0p = hp + (size_t)(b * 32 + nt0) * 16384 + lane * 8;
  const unsigned short* b1p = b0p + 16384;
  f32x16 acc00, acc01, acc10, acc11;
#pragma unroll
  for (int i = 0; i < 16; ++i) { acc00[i] = 0.f; acc01[i] = 0.f; acc10[i] = 0.f; acc11[i] = 0.f; }
#pragma unroll 2
  for (int kb = 0; kb < 32; ++kb) {
    const int off = kb * 512;
    const short8v a0 = *(const short8v*)(a0p + off);
    const short8v a1 = *(const short8v*)(a1p + off);
    const short8v b0 = *(const short8v*)(b0p + off);
    const short8v b1 = *(const short8v*)(b1p + off);
    acc00 = __builtin_amdgcn_mfma_f32_32x32x16_bf16(a0, b0, acc00, 0, 0, 0);
    acc01 = __builtin_amdgcn_mfma_f32_32x32x16_bf16(a0, b1, acc01, 0, 0, 0);
    acc10 = __builtin_amdgcn_mfma_f32_32x32x16_bf16(a1, b0, acc10, 0, 0, 0);
    acc11 = __builtin_amdgcn_mfma_f32_32x32x16_bf16(a1, b1, acc11, 0, 0, 0);
  }
  const int l31 = lane & 31, l5 = lane >> 5;
#pragma unroll
  for (int oi = 0; oi < 2; ++oi) {
#pragma unroll
    for (int nj = 0; nj < 2; ++nj) {
      const f32x16 a = (oi == 0) ? (nj == 0 ? acc00 : acc01)
                                 : (nj == 0 ? acc10 : acc11);
      const int ob = (ot0 + oi) * 32;
      const int nb = (nt0 + nj) * 32;
#pragma unroll
      for (int r16 = 0; r16 < 16; ++r16) {
        const int row = (r16 & 3) + 8 * (r16 >> 2) + 4 * l5;
        Y5[((size_t)(b << 10) + ob + row) * 1024 + nb + l31] = a[r16];
      }
    }
  }
}

// ---------------------------------------------------------------------------
// c1pool: one block per channel o; single HBM pass (rows staged in LDS).
// ---------------------------------------------------------------------------
__global__ __launch_bounds__(256) void c1pool_kernel(
    const float* __restrict__ Y5, const float* __restrict__ g,
    const float* __restrict__ bb, float* __restrict__ z) {
  __shared__ __align__(16) float s_y[8][1024];
  __shared__ float sr[256];
  __shared__ float s_par[2];
  const int o = blockIdx.x, t = threadIdx.x;
  float s1 = 0.f, s2 = 0.f;
#pragma unroll
  for (int b = 0; b < 8; ++b) {
    const float4 v = *(const float4*)&Y5[((size_t)((b << 10) + o)) * 1024 + t * 4];
    *(float4*)&s_y[b][t * 4] = v;
    s1 += v.x + v.y + v.z + v.w;
    s2 = fmaf(v.x, v.x, s2);
    s2 = fmaf(v.y, v.y, s2);
    s2 = fmaf(v.z, v.z, s2);
    s2 = fmaf(v.w, v.w, s2);
  }
  sr[t] = s1;
  __syncthreads();
  for (int s = 128; s > 0; s >>= 1) {
    if (t < s) sr[t] += sr[t + s];
    __syncthreads();
  }
  if (t == 0) s_par[0] = sr[0];
  __syncthreads();
  sr[t] = s2;
  __syncthreads();
  for (int s = 128; s > 0; s >>= 1) {
    if (t < s) sr[t] += sr[t + s];
    __syncthreads();
  }
  if (t == 0) {
    const float mean = s_par[0] * (1.f / 8192.f);
    const float var = sr[0] * (1.f / 8192.f) - mean * mean;
    const float sc = g[o] * rsqrtf(var + BNEPS);
    s_par[0] = sc;
    s_par[1] = bb[o] - mean * sc;
  }
  __syncthreads();
  const float sc = s_par[0], sh = s_par[1];
  const int lane = t & 63, w = t >> 6;
#pragma unroll
  for (int h = 0; h < 2; ++h) {
    const int b = w + h * 4;
    float mx = -3.4e38f, sm = 0.f;
#pragma unroll
    for (int j = 0; j < 4; ++j) {
      const float4 v = *(const float4*)&s_y[b][lane * 16 + j * 4];
      const float y0 = lrelu(fmaf(sc, v.x, sh));
      const float y1 = lrelu(fmaf(sc, v.y, sh));
      const float y2 = lrelu(fmaf(sc, v.z, sh));
      const float y3 = lrelu(fmaf(sc, v.w, sh));
      mx = fmaxf(fmaxf(fmaxf(mx, y0), fmaxf(y1, y2)), y3);
      sm += y0 + y1 + y2 + y3;
    }
#pragma unroll
    for (int off = 1; off < 64; off <<= 1) {
      mx = fmaxf(mx, __shfl_xor(mx, off, 64));
      sm += __shfl_xor(sm, off, 64);
    }
    if (lane == 0) {
      z[b * 2048 + o] = mx;
      z[b * 2048 + 1024 + o] = sm * (1.f / 1024.f);
    }
  }
}

// ---------------------------------------------------------------------------
// fallback f32 conv1d (used only if ws too small for MFMA buffers)
// ---------------------------------------------------------------------------
__global__ void bn_finalize_kernel(float* __restrict__ stats,
                                   const float* __restrict__ g,
                                   const float* __restrict__ bb, int cout,
                                   float inv_cnt) {
  const int o = blockIdx.x * 256 + threadIdx.x;
  if (o >= cout) return;
  const float mean = stats[o] * inv_cnt;
  const float var = stats[1024 + o] * inv_cnt - mean * mean;
  const float s = g[o] * rsqrtf(var + BNEPS);
  stats[2048 + o] = s;
  stats[3072 + o] = bb[o] - mean * s;
}

__global__ __launch_bounds__(256) void conv1d_gemm_kernel(
    const float* __restrict__ hcat, const float* __restrict__ WT5,
    float* __restrict__ stats, float* __restrict__ Y5) {
  __shared__ __align__(16) float s_w[8][64];
  __shared__ __align__(16) float s_h[8][64];
  __shared__ __align__(16) float s_red[64][16];
  const int t = threadIdx.x;
  const int bx = blockIdx.x;
  const int b = bx >> 8;
  const int o0 = ((bx >> 4) & 15) * 64;
  const int n0 = (bx & 15) * 64;
  const float* hb = hcat + (size_t)b * (512 * 1024);
  const int to = (t >> 4) * 4;
  const int tn = (t & 15) * 4;
  float acc[4][4] = {};
  for (int c0 = 0; c0 < 512; c0 += 8) {
    for (int i = t; i < 8 * 64; i += 256) {
      const int cc = i >> 6, col = i & 63;
      s_w[cc][col] = WT5[(c0 + cc) * 1024 + o0 + col];
      s_h[cc][col] = hb[(c0 + cc) * NN + n0 + col];
    }
    __syncthreads();
#pragma unroll
    for (int cc = 0; cc < 8; ++cc) {
      const float4 wv = *(const float4*)&s_w[cc][to];
      const float4 hv = *(const float4*)&s_h[cc][tn];
      const float wa[4] = {wv.x, wv.y, wv.z, wv.w};
      const float ha[4] = {hv.x, hv.y, hv.z, hv.w};
#pragma unroll
      for (int i = 0; i < 4; ++i)
#pragma unroll
        for (int j = 0; j < 4; ++j) acc[i][j] = fmaf(wa[i], ha[j], acc[i][j]);
    }
    __syncthreads();
  }
#pragma unroll
  for (int i = 0; i < 4; ++i) {
    *(float4*)&Y5[((size_t)(b << 10) + o0 + to + i) * NN + n0 + tn] =
        make_float4(acc[i][0], acc[i][1], acc[i][2], acc[i][3]);
  }
#pragma unroll
  for (int i = 0; i < 4; ++i)
    s_red[to + i][t & 15] = acc[i][0] + acc[i][1] + acc[i][2] + acc[i][3];
  __syncthreads();
  if (t < 64) {
    float s = 0.f;
#pragma unroll
    for (int g2 = 0; g2 < 16; ++g2) s += s_red[t][g2];
    atomicAdd(&stats[o0 + t], s);
  }
  __syncthreads();
#pragma unroll
  for (int i = 0; i < 4; ++i) {
    float s = 0.f;
#pragma unroll
    for (int j = 0; j < 4; ++j) s = fmaf(acc[i][j], acc[i][j], s);
    s_red[to + i][t & 15] = s;
  }
  __syncthreads();
  if (t < 64) {
    float s = 0.f;
#pragma unroll
    for (int g2 = 0; g2 < 16; ++g2) s += s_red[t][g2];
    atomicAdd(&stats[1024 + o0 + t], s);
  }
}

__global__ __launch_bounds__(256) void pool_kernel(
    const float* __restrict__ Y5, const float* __restrict__ stats,
    float* __restrict__ z) {
  const int t = threadIdx.x;
  const int lane = t & 63;
  const int bx = blockIdx.x;
  const int b = bx >> 8;
  const int o = (bx & 255) * 4 + (t >> 6);
  const float sc = stats[2048 + o], sh = stats[3072 + o];
  const float* yr = Y5 + ((size_t)(b << 10) + o) * NN;
  float mx = -3.4e38f, sm = 0.f;
#pragma unroll
  for (int j = 0; j < 16; ++j) {
    const float y = lrelu(fmaf(sc, yr[j * 64 + lane], sh));
    mx = fmaxf(mx, y);
    sm += y;
  }
  for (int off = 32; off > 0; off >>= 1) {
    mx = fmaxf(mx, __shfl_down(mx, off, 64));
    sm += __shfl_down(sm, off, 64);
  }
  if (lane == 0) {
    z[b * 2048 + o] = mx;
    z[b * 2048 + 1024 + o] = sm * (1.f / 1024.f);
  }
}

// ---------------------------------------------------------------------------
// MLP layer with batch-of-8 BN + lrelu fused. W/bias read RAW from inputs.
// ---------------------------------------------------------------------------
__global__ __launch_bounds__(256) void mlp_kernel(
    const float* __restrict__ zin, const void* __restrict__ W,
    const void* __restrict__ bias, const int* __restrict__ flags, int wfl,
    int bfl, const float* __restrict__ g, const float* __restrict__ bb,
    int kin, float* __restrict__ out, int O) {
  __shared__ float s_red[256];
  __shared__ float s_y[8];
  const int t = threadIdx.x;
  const int o = blockIdx.x;
  const int fw = flags[wfl];
  float acc[8];
#pragma unroll
  for (int b = 0; b < 8; ++b) acc[b] = 0.f;
  for (int c = t; c < kin; c += 256) {
    const float w = load_in(W, fw, o * kin + c);
#pragma unroll
    for (int b = 0; b < 8; ++b) acc[b] = fmaf(w, zin[b * kin + c], acc[b]);
  }
  for (int b = 0; b < 8; ++b) {
    s_red[t] = acc[b];
    __syncthreads();
    for (int s = 128; s > 0; s >>= 1) {
      if (t < s) s_red[t] += s_red[t + s];
      __syncthreads();
    }
    if (t == 0)
      s_y[b] = s_red[0] + (bias ? load_in(bias, flags[bfl], o) : 0.f);
    __syncthreads();
  }
  if (t == 0) {
    float m = 0.f;
    for (int b = 0; b < 8; ++b) m += s_y[b];
    m *= 0.125f;
    float v = 0.f;
    for (int b = 0; b < 8; ++b) { const float d = s_y[b] - m; v = fmaf(d, d, v); }
    v *= 0.125f;
    const float s = g[o] * rsqrtf(v + BNEPS);
    const float sh = bb[o] - m * s;
    for (int b = 0; b < 8; ++b) out[b * O + o] = lrelu(fmaf(s, s_y[b], sh));
  }
}

// final: out = z2 @ Wl3^T + bl3 (raw reads); output dtype from flags.
__global__ void final_kernel(const float* __restrict__ z2,
                             const void* __restrict__ Wl3,
                             const void* __restrict__ bl3,
                             const int* __restrict__ flags, void* out) {
  const int j = blockIdx.x * 256 + threadIdx.x;
  if (j >= 320) return;
  int anyf32 = 0, anybf = 0;
  for (int i = 0; i < NIN; ++i) {
    const int fl = flags[i];
    if (fl == 0) anyf32 = 1;
    if (fl == 1) anybf = 1;
  }
  const int bf16out = (anybf && !anyf32) ? 1 : 0;
  const int fw = flags[9], fb = flags[10];
  const int b = j / 40, o = j - b * 40;
  float s = load_in(bl3, fb, o);
  for (int c = 0; c < 256; ++c)
    s = fmaf(z2[b * 256 + c], load_in(Wl3, fw, o * 256 + c), s);
  if (bf16out) ((__hip_bfloat16*)out)[j] = __float2bfloat16(s);
  else ((float*)out)[j] = s;
}

// ---------------------------------------------------------------------------
template <int C, int O>
static void run_stage(float* wsf, const float* xbase, int bstr, int widx,
                      int gidx, int bidx, int stat, float* hout,
                      unsigned short* hp, int coff, hipStream_t stream) {
  int* idxb = reinterpret_cast<int*>(wsf + IDXo);
  float* U = wsf + U_OFF;
  float* Vd = wsf + VD_OFF;
  float* ysel = wsf + YS_OFF;
  float* stats = wsf + STATSo + stat * 4096;
  tg_kernel<C, O><<<512 + BB * 16 * (O / 64), 512, 0, stream>>>(
      xbase, bstr, wsf + widx, U, Vd, idxb);
  edge_pass_kernel<O><<<512, 256, 0, stream>>>(U, Vd, idxb, wsf + gidx, stats,
                                               ysel);
  bn_apply_kernel<O><<<BB * 32 * (O / 32), 256, 0, stream>>>(
      ysel, stats, wsf + gidx, wsf + bidx, hout, hp, coff);
}

extern "C" void kernel_launch(void* const* d_in, const int* in_sizes, int n_in,
                              void* d_out, int out_size, void* d_ws,
                              size_t ws_size, hipStream_t stream) {
  (void)in_sizes; (void)n_in; (void)out_size;
  float* wsf = reinterpret_cast<float*>(d_ws);
  int* flags = reinterpret_cast<int*>(wsf + FLAGSo);
  float* hcat = wsf + HCATo;
  const bool mf = ws_size >= WS_NEED_MFMA;
  unsigned short* hp = mf ? reinterpret_cast<unsigned short*>(wsf + HBFo) : nullptr;
  unsigned short* w5p = reinterpret_cast<unsigned short*>(wsf + W5BFo);

  Ptrs ptrs;
  for (int i = 0; i < NIN; ++i) ptrs.p[i] = d_in[i];

  detect_kernel<<<NIN, 64, 0, stream>>>(ptrs, flags);
  const int nmain = mf ? NMAIN_MF : NCONV;
  convert_kernel<<<nmain + 80 + 256, 256, 0, stream>>>(ptrs, flags, wsf,
                                                       mf ? 1 : 0, nmain);

  run_stage<3, 64>(wsf, wsf + XIN, 3 * NN, WT1, G1, B1o, 0, hcat, hp, 0,
                   stream);
  run_stage<64, 64>(wsf, hcat, 512 * NN, WT2, G2, B2o, 1, hcat + 64 * NN, hp,
                    64, stream);
  run_stage<64, 128>(wsf, hcat + 64 * NN, 512 * NN, WT3, G3, B3o, 2,
                     hcat + 128 * NN, hp, 128, stream);
  // stage 4: f32 hout is dead in the MFMA path (only packed hp consumed)
  run_stage<128, 256>(wsf, hcat + 128 * NN, 512 * NN, WT4, G4, B4o, 3,
                      mf ? nullptr : (hcat + 256 * NN), hp, 256, stream);

  // conv1d 512->1024 + BN + pool
  float* Y5 = wsf + Y5_OFF;
  float* st5 = wsf + STATSo + 4 * 4096;
  if (mf) {
    conv1d_mfma_kernel<<<512, 256, 0, stream>>>(hp, w5p, Y5);
    c1pool_kernel<<<1024, 256, 0, stream>>>(Y5, wsf + G5, wsf + B5o,
                                            wsf + Z2048o);
  } else {
    conv1d_gemm_kernel<<<2048, 256, 0, stream>>>(hcat, wsf + WT5, st5, Y5);
    bn_finalize_kernel<<<4, 256, 0, stream>>>(st5, wsf + G5, wsf + B5o, 1024,
                                              1.f / 8192.f);
    pool_kernel<<<BB * 256, 256, 0, stream>>>(Y5, st5, wsf + Z2048o);
  }

  // MLP head (raw W/bias reads)
  mlp_kernel<<<512, 256, 0, stream>>>(wsf + Z2048o, d_in[6], nullptr, flags,
      6, 0, wsf + G6, wsf + B6o, 2048, wsf + Z1o, 512);
  mlp_kernel<<<256, 256, 0, stream>>>(wsf + Z1o, d_in[7], d_in[8], flags,
      7, 8, wsf + G7, wsf + B7o, 512, wsf + Z2o, 256);
  final_kernel<<<2, 256, 0, stream>>>(wsf + Z2o, d_in[9], d_in[10],
      flags, d_out);
}

// Round 18
// 393.471 us; speedup vs baseline: 1.1425x; 1.0527x over previous
//
#include <hip/hip_runtime.h>
#include <hip/hip_bf16.h>
#include <cstdint>

// ---------------------------------------------------------------------------
// DGCNN forward on MI355X. Math f32; conv1d via bf16 MFMA on packed
// fragment layouts; kNN via FUSED dist+topk.
// R31: vectorize fused-tg B reads to ds_read_b128. R30 counters (conflicts
// 0, HBM 4%, occ 2x with flat duration) => LDS-throughput-bound: each wave
// reads the full 4KB B-row per cc as 16 scalar ds_read_b32 (~27 TB/s chip
// effective) -> stage-4 fused LDS ~2GB ~74us. Now lane owns cols
// {4*lane+256q+r}: 4x float4 reads, contiguous 1KB/wave pattern
// (conflict-free, ~85 B/cyc) -> LDS time ~halves, 12 fewer VALU ops/cc.
// Exactness: per-(row,col) FMA order unchanged -> identical keys; threshold
// proof partition-independent; rank on global composite -> identical idxb.
// ci = 4*lane+256*(j>>2)+(j&3); fallback inverse j = 4*(ci>>8)+(ci&3).
// Kept: R30 512-thread fused blocks (8 waves x 2 rows), interleaved search,
// banked stats atomics + 8-bank bn sum, edge XCD batch affinity, convert
// compaction + raw MLP reads, c1pool single-pass, stage-4 hout skip.
// ---------------------------------------------------------------------------

static constexpr int BB  = 8;
static constexpr int NN  = 1024;
static constexpr int KNB = 20;
static constexpr float BNEPS = 1e-5f;

static constexpr int NIN = 25;

__constant__ int c_cum[NIN + 1] = {
    0, 24576, 24960, 33152, 49536, 115072, 639360,
    1687936, 1819008, 1819264, 1829504, 1829544, 1829608, 1829672, 1829736,
    1829800, 1829928, 1830056, 1830312, 1830568, 1831592, 1832616, 1833128,
    1833640, 1833896, 1834152};
__constant__ int c_trO[NIN] = {0, 64, 64, 128, 256, 1024, 0, 0, 0, 0, 0,
                               0, 0, 0, 0, 0, 0, 0, 0, 0, 0, 0, 0, 0, 0};
__constant__ int c_trI[NIN] = {0, 6, 128, 128, 256, 512, 0, 0, 0, 0, 0,
                               0, 0, 0, 0, 0, 0, 0, 0, 0, 0, 0, 0, 0, 0};

enum : int {
  XIN = 0, WT1 = 24576, WT2 = 24960, WT3 = 33152, WT4 = 49536, WT5 = 115072,
  WL1 = 639360, WL2 = 1687936, BL2o = 1819008, WL3 = 1819264, BL3o = 1829504,
  G1 = 1829544, B1o = 1829608, G2 = 1829672, B2o = 1829736,
  G3 = 1829800, B3o = 1829928, G4 = 1830056, B4o = 1830312,
  G5 = 1830568, B5o = 1831592, G6 = 1832616, B6o = 1833128,
  G7 = 1833640, B7o = 1833896,
  IDXo = 1842432,       // 163840 i32
  HCATo = 2006272,      // 8*512*1024 f
  STATSo = 6200576,     // 5 layers * 4096 f (stages 0-3: 8-banked partials)
  Z2048o = 6237440,     // 8*2048 f
  Z1o = 6253824,        // 8*512 f
  Z2o = 6257920,        // 8*256 f
  FLAGSo = 6259968,     // 32 i32
  DISTo = 6260736,      // window (U/Vd/ysel; D not materialized)
  HBFo  = 14649344,     // packed bf16 h: 8*1024*512 shorts (2M float slots)
  W5BFo = 16746496      // packed bf16 w5: 512K shorts -> ends 17008640
};
static constexpr int TOTAL_IN = 1834152;
static constexpr int NCONV = (TOTAL_IN + 255) / 256;   // full-copy blocks (!mf)
static constexpr int NMAIN_ELEMS = 115072 + 4608;      // 119680
static constexpr int NMAIN_MF = (NMAIN_ELEMS + 255) / 256;  // 468 blocks
static constexpr int U_OFF   = DISTo + 0;
static constexpr int VD_OFF  = DISTo + 2097152;
static constexpr int YS_OFF  = DISTo + 4194304;
static constexpr int Y5_OFF  = DISTo + 0;
static constexpr size_t WS_NEED_MFMA = (size_t)17008640 * 4;  // ~68 MB

struct Ptrs { const void* p[NIN]; };

typedef short short8v __attribute__((ext_vector_type(8)));
typedef float f32x16 __attribute__((ext_vector_type(16)));

__device__ __forceinline__ float lrelu(float y) { return (y < 0.f) ? 0.2f * y : y; }
__device__ __forceinline__ unsigned short f2b(float f) {
  unsigned u = __float_as_uint(f);
  unsigned r = (u + 0x7FFFu + ((u >> 16) & 1u)) >> 16;   // RNE
  return (unsigned short)r;
}
// sortable key: monotone map float -> u32 (larger float -> larger key)
__device__ __forceinline__ unsigned f2s(float f) {
  const unsigned s = __float_as_uint(f);
  return s ^ ((unsigned)((int)s >> 31) | 0x80000000u);
}
__device__ __forceinline__ float load_in(const void* p, int fl, int idx) {
  if (fl == 2) return 0.f;
  if (fl == 1) {
    const unsigned short u = ((const unsigned short*)p)[idx];
    return __uint_as_float(((unsigned)u) << 16);
  }
  return ((const float*)p)[idx];
}
__device__ __forceinline__ int mbcnt64(unsigned long long m) {
  return __builtin_amdgcn_mbcnt_hi((unsigned)(m >> 32),
                                   __builtin_amdgcn_mbcnt_lo((unsigned)m, 0));
}

// ---------------------------------------------------------------------------
// dtype detection
// ---------------------------------------------------------------------------
__global__ void detect_kernel(Ptrs ptrs, int* __restrict__ flags) {
  const int i = blockIdx.x;
  const unsigned* p = (const unsigned*)ptrs.p[i];
  const int n = c_cum[i + 1] - c_cum[i];
  int words = n >> 1; if (words > 64) words = 64;
  const int t = threadIdx.x;
  unsigned w = (t < words) ? p[t] : 0u;
  bool nz = (w != 0u);
  unsigned e = (w >> 7) & 0xFFu;
  bool pl = nz && (e >= 96u) && (e <= 140u);
  unsigned long long mnz = __ballot(nz);
  unsigned long long mpl = __ballot(pl);
  if (t == 0) {
    int cnz = __popcll(mnz), cpl = __popcll(mpl);
    flags[i] = (cnz == 0) ? 2 : ((2 * cpl > words) ? 1 : 0);
  }
}

// ---------------------------------------------------------------------------
// convert: main blocks convert+transpose inputs; tail1 zeroes stats;
// tail2 packs w5 (raw input -> MFMA A-fragment bf16) if do_w5.
// ---------------------------------------------------------------------------
__global__ void convert_kernel(Ptrs ptrs, const int* __restrict__ flags,
                               float* __restrict__ ws, int do_w5, int nmain) {
  const int bx = blockIdx.x;
  const int t = threadIdx.x;
  if (bx >= nmain + 80) {            // tail2: w5 packing
    if (!do_w5) return;
    const int g = (bx - nmain - 80) * 256 + t;   // 0..65535
    const int lane = g & 63;
    const int kb = (g >> 6) & 31;
    const int ot = g >> 11;
    const int o = ot * 32 + (lane & 31);
    const int k0 = kb * 16 + (lane >> 5) * 8;
    const void* w5raw = ptrs.p[5];
    const int fl = flags[5];
    unsigned u[4];
#pragma unroll
    for (int h = 0; h < 4; ++h) {
      const unsigned short lo = f2b(load_in(w5raw, fl, o * 512 + k0 + 2 * h));
      const unsigned short hi = f2b(load_in(w5raw, fl, o * 512 + k0 + 2 * h + 1));
      u[h] = (unsigned)lo | ((unsigned)hi << 16);
    }
    unsigned short* w5p = (unsigned short*)(ws + W5BFo);
    *(uint4*)&w5p[(size_t)g * 8] = make_uint4(u[0], u[1], u[2], u[3]);
    return;
  }
  if (bx >= nmain) {                 // tail1: zero stats
    const int z = (bx - nmain) * 256 + t;
    if (z < 20480) ws[STATSo + z] = 0.f;
    return;
  }
  int e;
  if (do_w5) {                       // compact map
    const int e2 = bx * 256 + t;
    if (e2 >= NMAIN_ELEMS) return;
    e = (e2 < 115072) ? e2 : (e2 - 115072 + 1829544);
  } else {
    e = bx * 256 + t;
    if (e >= TOTAL_IN) return;
  }
  int i = 0;
  while (e >= c_cum[i + 1]) ++i;
  const int el = e - c_cum[i];
  int src;
  const int O = c_trO[i];
  if (O > 0) {
    const int I = c_trI[i];
    const int o = el % O, ii = el / O;
    src = o * I + ii;
  } else src = el;
  ws[e] = load_in(ptrs.p[i], flags[i], src);
}

// ---------------------------------------------------------------------------
// merged FUSED dist+topk (blocks 0..511) + gemm_uv (blocks 512..).
// 512 threads/block. Fused: 16 rows/block, 8 waves x 2 rows; lane owns
// cols {4*lane+256q+r} -> B reads are 4x ds_read_b128, contiguous
// 1KB/wave (conflict-free). gemm_uv retiled 2x4/thread.
// ---------------------------------------------------------------------------
template <int C, int O>
__global__ __launch_bounds__(512) void tg_kernel(
    const float* __restrict__ xbase, int bstr, const float* __restrict__ WT,
    float* __restrict__ U, float* __restrict__ Vd, int* __restrict__ idxb) {
  constexpr int OT = O / 64;
  __shared__ __align__(16) float s_mem[8 * 1024 + 128 + 1024];
  const int t = threadIdx.x;
  if (blockIdx.x < 512) {
    float (*s_b)[1024] = (float(*)[1024])s_mem;
    float (*s_a)[8] = (float(*)[8])(s_mem + 8192);
    float* s_xx = s_mem + 8192 + 128;
    const int b = blockIdx.x & 7;          // batch (XCD-affine)
    const int rg = blockIdx.x >> 3;        // 0..63
    const int r0 = rg * 16;
    const float* xb = xbase + (size_t)b * bstr;
    const int wv = t >> 6, lane = t & 63;  // wv 0..7
    float acc[2][16] = {};
    float xxa[2] = {0.f, 0.f};
    for (int c0 = 0; c0 < C; c0 += 8) {
      const int kc = (C - c0 < 8) ? (C - c0) : 8;
      __syncthreads();
      for (int i = t; i < 2048; i += 512) {          // B: [8][1024] (zero-pad)
        const int cc = i >> 8, col4 = (i & 255) * 4;
        float4 v = make_float4(0.f, 0.f, 0.f, 0.f);
        if (cc < kc) v = *(const float4*)&xb[(c0 + cc) * NN + col4];
        *(float4*)&s_b[cc][col4] = v;
      }
      if (t < 128) {                                  // A: [16][8]
        const int rr = t >> 3, cc = t & 7;
        s_a[rr][cc] = (cc < kc) ? xb[(c0 + cc) * NN + r0 + rr] : 0.f;
      }
      __syncthreads();
#pragma unroll
      for (int cc = 0; cc < 8; ++cc) {
        float a2[2];
#pragma unroll
        for (int ri = 0; ri < 2; ++ri) a2[ri] = s_a[wv * 2 + ri][cc];
        float bv[16];
#pragma unroll
        for (int q = 0; q < 4; ++q) {                // 4x ds_read_b128
          const float4 v = *(const float4*)&s_b[cc][4 * lane + 256 * q];
          bv[4 * q + 0] = v.x;
          bv[4 * q + 1] = v.y;
          bv[4 * q + 2] = v.z;
          bv[4 * q + 3] = v.w;
        }
#pragma unroll
        for (int ri = 0; ri < 2; ++ri)
#pragma unroll
          for (int j = 0; j < 16; ++j)
            acc[ri][j] = fmaf(a2[ri], bv[j], acc[ri][j]);
#pragma unroll
        for (int q = 0; q < 2; ++q) {                // col-norm partials
          const float v = s_b[cc][q * 512 + t];
          xxa[q] = fmaf(v, v, xxa[q]);
        }
      }
    }
    __syncthreads();
#pragma unroll
    for (int q = 0; q < 2; ++q) s_xx[q * 512 + t] = xxa[q];
    __syncthreads();
    float xm[16];
#pragma unroll
    for (int q = 0; q < 4; ++q) {
      const float4 v = *(const float4*)&s_xx[4 * lane + 256 * q];
      xm[4 * q + 0] = v.x;
      xm[4 * q + 1] = v.y;
      xm[4 * q + 2] = v.z;
      xm[4 * q + 3] = v.w;
    }
    unsigned long long* scw = (unsigned long long*)s_mem + wv * 128;
    // ---- keys for both rows (acc dead after -> regs reused) ----
    unsigned k16a[2][16];
    unsigned lmax2[2];
#pragma unroll
    for (int ri = 0; ri < 2; ++ri) {
      const float xxn = s_xx[r0 + wv * 2 + ri];
      unsigned lm = 0u;
#pragma unroll
      for (int j = 0; j < 16; ++j) {
        k16a[ri][j] = f2s(2.f * acc[ri][j] - xxn - xm[j]);
        lm = (k16a[ri][j] > lm) ? k16a[ri][j] : lm;
      }
      lmax2[ri] = lm;
    }
    // ---- interleaved binary search: 2 independent ballots per iter ----
    unsigned T2[2] = {0u, 0u};
    for (int bb2 = 31; bb2 >= 0; --bb2) {
#pragma unroll
      for (int ri = 0; ri < 2; ++ri) {
        const unsigned cand = T2[ri] | (1u << bb2);
        if (__popcll(__ballot(lmax2[ri] >= cand)) >= KNB) T2[ri] = cand;
      }
    }
    // ---- per-row tails (compact / rank / scatter) ----
#pragma unroll
    for (int ri = 0; ri < 2; ++ri) {     // UNROLLED: static indices (rule #20)
      const int rowg = (b << 10) + r0 + wv * 2 + ri;
      const unsigned T = T2[ri];
      int cnt = 0;
#pragma unroll
      for (int j = 0; j < 16; ++j) cnt += (k16a[ri][j] >= T) ? 1 : 0;
      int n_c = 0, off = 0;
#pragma unroll
      for (int bb2 = 0; bb2 < 5; ++bb2) {
        const unsigned long long m = __ballot((cnt >> bb2) & 1);
        n_c += __popcll(m) << bb2;
        off += mbcnt64(m) << bb2;
      }
      if (n_c <= 128) {
#pragma unroll
        for (int j = 0; j < 16; ++j)
          if (k16a[ri][j] >= T) {
            const int ci = 4 * lane + 256 * (j >> 2) + (j & 3);
            scw[off] = (((unsigned long long)k16a[ri][j]) << 32) |
                       (unsigned long long)(0xFFFFFFFFu ^ (unsigned)ci);
            ++off;
          }
        if (n_c <= 64) {
          unsigned long long mye = 0ULL;
          if (lane < n_c) mye = scw[lane];
          int rank = 0;
          for (int j = 0; j < n_c; ++j) {
            const unsigned eh =
                (unsigned)__builtin_amdgcn_readlane((int)(mye >> 32), j);
            const unsigned el =
                (unsigned)__builtin_amdgcn_readlane((int)(mye & 0xFFFFFFFFu), j);
            const unsigned long long ej = (((unsigned long long)eh) << 32) | el;
            rank += (ej > mye) ? 1 : 0;
          }
          if (lane < n_c && rank < KNB)
            idxb[rowg * KNB + rank] =
                (int)(0xFFFFFFFFu ^ (unsigned)(mye & 0xFFFFFFFFu));
        } else {
          const unsigned long long mye = (lane < n_c) ? scw[lane] : 0ULL;
          const unsigned long long mye2 =
              (64 + lane < n_c) ? scw[64 + lane] : 0ULL;
          int r1 = 0, r2 = 0;
          for (int j = 0; j < n_c; ++j) {
            const unsigned long long ej = scw[j];   // broadcast read
            r1 += (ej > mye) ? 1 : 0;
            r2 += (ej > mye2) ? 1 : 0;
          }
          if (lane < n_c && r1 < KNB)
            idxb[rowg * KNB + r1] = (int)(0xFFFFFFFFu ^ (unsigned)mye);
          if (64 + lane < n_c && r2 < KNB)
            idxb[rowg * KNB + r2] = (int)(0xFFFFFFFFu ^ (unsigned)mye2);
        }
      } else {
        // ---- composite-u64 extraction fallback (exact; ~never) ----
        unsigned long long q[4] = {0ULL, 0ULL, 0ULL, 0ULL};
        unsigned emit = 0;
#pragma unroll
        for (int j = 0; j < 16; ++j) {
          const int ci = 4 * lane + 256 * (j >> 2) + (j & 3);
          const unsigned long long c =
              (((unsigned long long)k16a[ri][j]) << 32) |
              (unsigned long long)(0xFFFFFFFFu ^ (unsigned)ci);
          if (c > q[3]) {
            q[3] = c;
            if (q[3] > q[2]) { auto tv = q[2]; q[2] = q[3]; q[3] = tv; }
            if (q[2] > q[1]) { auto tv = q[1]; q[1] = q[2]; q[2] = tv; }
            if (q[1] > q[0]) { auto tv = q[0]; q[0] = q[1]; q[1] = tv; }
          }
        }
        for (int kk = 0; kk < KNB; ++kk) {
          unsigned long long best = q[0];
          for (int o2 = 1; o2 < 64; o2 <<= 1) {
            const unsigned long long p =
                (unsigned long long)__shfl_xor((long long)best, o2, 64);
            best = (p > best) ? p : best;
          }
          if (lane == 0)
            idxb[rowg * KNB + kk] = (int)(0xFFFFFFFFu ^ (unsigned)best);
          if (q[0] == best) {           // unique owner (idx in composite)
            const int ci = (int)(0xFFFFFFFFu ^ (unsigned)best);
            const int j = 4 * (ci >> 8) + (ci & 3);
            emit |= 1u << j;
            q[0] = q[1]; q[1] = q[2]; q[2] = q[3]; q[3] = 0ULL;
            if (q[0] == 0ULL && __popc(emit) < 16) {
              for (int j2 = 0; j2 < 16; ++j2)
                if (!((emit >> j2) & 1u)) {
                  const int ci2 = 4 * lane + 256 * (j2 >> 2) + (j2 & 3);
                  const unsigned long long c2 =
                      (((unsigned long long)k16a[ri][j2]) << 32) |
                      (unsigned long long)(0xFFFFFFFFu ^ (unsigned)ci2);
                  if (c2 > q[3]) {
                    q[3] = c2;
                    if (q[3] > q[2]) { auto tv = q[2]; q[2] = q[3]; q[3] = tv; }
                    if (q[2] > q[1]) { auto tv = q[1]; q[1] = q[2]; q[2] = tv; }
                    if (q[1] > q[0]) { auto tv = q[0]; q[0] = q[1]; q[1] = tv; }
                  }
                }
            }
          }
        }
      }
    }
    return;
  }
  // ---- gemm_uv part (512 threads: 2x4 micro-tile; LDS aliased) ----
  float (*s_x)[64] = (float(*)[64])(s_mem);
  float (*s_wn)[64] = (float(*)[64])(s_mem + 512);
  float (*s_wc)[64] = (float(*)[64])(s_mem + 1024);
  const int bx = blockIdx.x - 512;
  const int b = bx / (16 * OT);
  const int r = bx % (16 * OT);
  const int n0 = (r / OT) * 64;
  const int o0 = (r % OT) * 64;
  const float* xb = xbase + (size_t)b * bstr;
  const int tn = (t >> 4) * 2;          // 0,2,..,62
  const int to = (t & 15) * 4;          // 0,4,..,60
  float accU[2][4] = {}, accC[2][4] = {};
  for (int c0 = 0; c0 < C; c0 += 8) {
    const int kc = (C - c0 < 8) ? (C - c0) : 8;
    {
      const int i = t;                  // one element per thread covers [8][64]
      const int cc = i >> 6, col = i & 63;
      const bool ok = cc < kc;
      s_x[cc][col]  = ok ? xb[(c0 + cc) * NN + n0 + col] : 0.f;
      s_wn[cc][col] = ok ? WT[(c0 + cc) * O + o0 + col] : 0.f;
      s_wc[cc][col] = ok ? WT[(C + c0 + cc) * O + o0 + col] : 0.f;
    }
    __syncthreads();
#pragma unroll
    for (int cc = 0; cc < 8; ++cc) {
      const float xa[2] = {s_x[cc][tn], s_x[cc][tn + 1]};
      const float4 wn = *(const float4*)&s_wn[cc][to];
      const float4 wc = *(const float4*)&s_wc[cc][to];
      const float na[4] = {wn.x, wn.y, wn.z, wn.w};
      const float ca[4] = {wc.x, wc.y, wc.z, wc.w};
#pragma unroll
      for (int i = 0; i < 2; ++i)
#pragma unroll
        for (int j = 0; j < 4; ++j) {
          accU[i][j] = fmaf(xa[i], na[j], accU[i][j]);
          accC[i][j] = fmaf(xa[i], ca[j], accC[i][j]);
        }
    }
    __syncthreads();
  }
#pragma unroll
  for (int i = 0; i < 2; ++i) {
    const size_t base2 = ((size_t)(b << 10) + n0 + tn + i) * O + o0 + to;
    *(float4*)&U[base2] = make_float4(accU[i][0], accU[i][1], accU[i][2], accU[i][3]);
    *(float4*)&Vd[base2] = make_float4(accC[i][0] - accU[i][0], accC[i][1] - accU[i][1],
                                       accC[i][2] - accU[i][2], accC[i][3] - accU[i][3]);
  }
}

// ---------------------------------------------------------------------------
// edge gather pass (XCD batch affinity: block bx serves batch bx&7).
// Grid 512 (atomic-tail-pinned); stats banked 8-ways by (bx&7).
// ---------------------------------------------------------------------------
template <int O>
__global__ __launch_bounds__(256) void edge_pass_kernel(
    const float* __restrict__ U, const float* __restrict__ Vd,
    const int* __restrict__ idxb, const float* __restrict__ g,
    float* __restrict__ stats, float* __restrict__ ysel) {
  constexpr int PSUB = 256 / O;
  __shared__ float s_red[256];
  const int t = threadIdx.x;
  const int o = t & (O - 1);
  const int psub = t / O;
  const bool usemax = g[o] >= 0.f;
  const int bsel = blockIdx.x & 7;            // batch == presumed XCD
  const int wb = blockIdx.x >> 3;             // 0..63 within batch
  float* st1 = stats + bsel * 256;            // banked partials
  float* st2 = stats + 2048 + bsel * 256;
  const float* ub = U + ((size_t)(bsel << 10)) * O;
  float ls1 = 0.f, ls2 = 0.f;
  for (int pl = wb * PSUB + psub; pl < NN; pl += 64 * PSUB) {
    const int p = (bsel << 10) + pl;
    int id[KNB];
#pragma unroll
    for (int k = 0; k < KNB; ++k) id[k] = idxb[p * KNB + k];
    const float vd = Vd[(size_t)p * O + o];
    float ymx = -3.4e38f, ymn = 3.4e38f;
#pragma unroll
    for (int k = 0; k < KNB; ++k) {
      const float y = ub[(size_t)id[k] * O + o] + vd;
      ymx = fmaxf(ymx, y);
      ymn = fminf(ymn, y);
      ls1 += y;
      ls2 = fmaf(y, y, ls2);
    }
    ysel[(size_t)p * O + o] = usemax ? ymx : ymn;
  }
  if (PSUB == 1) {
    atomicAdd(&st1[o], ls1);
    atomicAdd(&st2[o], ls2);
  } else {
    s_red[t] = ls1;
    __syncthreads();
    if (t < O) {
      float s = s_red[t];
#pragma unroll
      for (int p2 = 1; p2 < PSUB; ++p2) s += s_red[t + p2 * O];
      atomicAdd(&st1[t], s);
    }
    __syncthreads();
    s_red[t] = ls2;
    __syncthreads();
    if (t < O) {
      float s = s_red[t];
#pragma unroll
      for (int p2 = 1; p2 < PSUB; ++p2) s += s_red[t + p2 * O];
      atomicAdd(&st2[t], s);
    }
  }
}

// ---------------------------------------------------------------------------
// bn_apply (finalize inlined, sums 8 stats banks) + transpose; packed bf16
// write for conv1d MFMA. hout may be null (stage 4 MFMA path: dead store).
// ---------------------------------------------------------------------------
template <int O>
__global__ __launch_bounds__(256) void bn_apply_kernel(
    const float* __restrict__ ysel, const float* __restrict__ stats,
    const float* __restrict__ g, const float* __restrict__ bb,
    float* __restrict__ hout, unsigned short* __restrict__ hp, int coff) {
  constexpr int OT = O / 32;
  __shared__ float s_t[32][33];
  const int t = threadIdx.x;
  const int bx = blockIdx.x;
  const int b = bx / (32 * OT);
  const int r = bx % (32 * OT);
  const int n0 = (r / OT) * 32;
  const int o0 = (r % OT) * 32;
  const int col = t & 31, rowb = t >> 5;
  const int o = o0 + col;
  const float inv = 1.f / (8.f * 1024.f * 20.f);
  float sum1 = 0.f, sum2 = 0.f;
#pragma unroll
  for (int j = 0; j < 8; ++j) {
    sum1 += stats[j * 256 + o];
    sum2 += stats[2048 + j * 256 + o];
  }
  const float mean = sum1 * inv;
  const float var = sum2 * inv - mean * mean;
  const float sc = g[o] * rsqrtf(var + BNEPS);
  const float sh = bb[o] - mean * sc;
  const int c = coff + o;               // conv1d K index
#pragma unroll
  for (int rr = 0; rr < 4; ++rr) {
    const int nl = n0 + rowb + rr * 8;
    const float y = ysel[((size_t)(b << 10) + nl) * O + o];
    const float h = lrelu(fmaf(sc, y, sh));
    if (hout) s_t[rowb + rr * 8][col] = h;
    if (hp) {
      const int lane2 = (nl & 31) + ((c >> 3) & 1) * 32;
      hp[(((size_t)(b * 32 + (nl >> 5)) * 32 + (c >> 4)) * 64 + lane2) * 8 +
         (c & 7)] = f2b(h);
    }
  }
  if (hout) {
    __syncthreads();
#pragma unroll
    for (int rr = 0; rr < 4; ++rr) {
      const int ol = rowb + rr * 8;
      hout[(size_t)b * (512 * 1024) + (o0 + ol) * NN + n0 + col] = s_t[col][ol];
    }
  }
}

// ---------------------------------------------------------------------------
// conv1d via MFMA on packed fragments: Y5[b][o][n] = sum_c W5[o][c]*h[b][n][c]
// ---------------------------------------------------------------------------
__global__ __launch_bounds__(256) void conv1d_mfma_kernel(
    const unsigned short* __restrict__ hp,
    const unsigned short* __restrict__ w5p, float* __restrict__ Y5) {
  const int t = threadIdx.x, bx = blockIdx.x;
  const int b = bx >> 6;
  const int r = bx & 63;
  const int w = t >> 6, lane = t & 63;
  const int ot0 = (r >> 3) * 4 + (w & 1) * 2;
  const int nt0 = (r & 7) * 4 + (w >> 1) * 2;
  const unsigned short* a0p = w5p + (size_t)ot0 * 16384 + lane * 8;
  const unsigned short* a1p = a0p + 16384;
  const unsigned short* b0p = hp + (size_t)(b * 32 + nt0) * 16384 + lane * 8;
  const unsigned short* b1p = b0p + 16384;
  f32x16 acc00, acc01, acc10, acc11;
#pragma unroll
  for (int i = 0; i < 16; ++i) { acc00[i] = 0.f; acc01[i] = 0.f; acc10[i] = 0.f; acc11[i] = 0.f; }
#pragma unroll 2
  for (int kb = 0; kb < 32; ++kb) {
    const int off = kb * 512;
    const short8v a0 = *(const short8v*)(a0p + off);
    const short8v a1 = *(const short8v*)(a1p + off);
    const short8v b0 = *(const short8v*)(b0p + off);
    const short8v b1 = *(const short8v*)(b1p + off);
    acc00 = __builtin_amdgcn_mfma_f32_32x32x16_bf16(a0, b0, acc00, 0, 0, 0);
    acc01 = __builtin_amdgcn_mfma_f32_32x32x16_bf16(a0, b1, acc01, 0, 0, 0);
    acc10 = __builtin_amdgcn_mfma_f32_32x32x16_bf16(a1, b0, acc10, 0, 0, 0);
    acc11 = __builtin_amdgcn_mfma_f32_32x32x16_bf16(a1, b1, acc11, 0, 0, 0);
  }
  const int l31 = lane & 31, l5 = lane >> 5;
#pragma unroll
  for (int oi = 0; oi < 2; ++oi) {
#pragma unroll
    for (int nj = 0; nj < 2; ++nj) {
      const f32x16 a = (oi == 0) ? (nj == 0 ? acc00 : acc01)
                                 : (nj == 0 ? acc10 : acc11);
      const int ob = (ot0 + oi) * 32;
      const int nb = (nt0 + nj) * 32;
#pragma unroll
      for (int r16 = 0; r16 < 16; ++r16) {
        const int row = (r16 & 3) + 8 * (r16 >> 2) + 4 * l5;
        Y5[((size_t)(b << 10) + ob + row) * 1024 + nb + l31] = a[r16];
      }
    }
  }
}

// ---------------------------------------------------------------------------
// c1pool: one block per channel o; single HBM pass (rows staged in LDS).
// ---------------------------------------------------------------------------
__global__ __launch_bounds__(256) void c1pool_kernel(
    const float* __restrict__ Y5, const float* __restrict__ g,
    const float* __restrict__ bb, float* __restrict__ z) {
  __shared__ __align__(16) float s_y[8][1024];
  __shared__ float sr[256];
  __shared__ float s_par[2];
  const int o = blockIdx.x, t = threadIdx.x;
  float s1 = 0.f, s2 = 0.f;
#pragma unroll
  for (int b = 0; b < 8; ++b) {
    const float4 v = *(const float4*)&Y5[((size_t)((b << 10) + o)) * 1024 + t * 4];
    *(float4*)&s_y[b][t * 4] = v;
    s1 += v.x + v.y + v.z + v.w;
    s2 = fmaf(v.x, v.x, s2);
    s2 = fmaf(v.y, v.y, s2);
    s2 = fmaf(v.z, v.z, s2);
    s2 = fmaf(v.w, v.w, s2);
  }
  sr[t] = s1;
  __syncthreads();
  for (int s = 128; s > 0; s >>= 1) {
    if (t < s) sr[t] += sr[t + s];
    __syncthreads();
  }
  if (t == 0) s_par[0] = sr[0];
  __syncthreads();
  sr[t] = s2;
  __syncthreads();
  for (int s = 128; s > 0; s >>= 1) {
    if (t < s) sr[t] += sr[t + s];
    __syncthreads();
  }
  if (t == 0) {
    const float mean = s_par[0] * (1.f / 8192.f);
    const float var = sr[0] * (1.f / 8192.f) - mean * mean;
    const float sc = g[o] * rsqrtf(var + BNEPS);
    s_par[0] = sc;
    s_par[1] = bb[o] - mean * sc;
  }
  __syncthreads();
  const float sc = s_par[0], sh = s_par[1];
  const int lane = t & 63, w = t >> 6;
#pragma unroll
  for (int h = 0; h < 2; ++h) {
    const int b = w + h * 4;
    float mx = -3.4e38f, sm = 0.f;
#pragma unroll
    for (int j = 0; j < 4; ++j) {
      const float4 v = *(const float4*)&s_y[b][lane * 16 + j * 4];
      const float y0 = lrelu(fmaf(sc, v.x, sh));
      const float y1 = lrelu(fmaf(sc, v.y, sh));
      const float y2 = lrelu(fmaf(sc, v.z, sh));
      const float y3 = lrelu(fmaf(sc, v.w, sh));
      mx = fmaxf(fmaxf(fmaxf(mx, y0), fmaxf(y1, y2)), y3);
      sm += y0 + y1 + y2 + y3;
    }
#pragma unroll
    for (int off = 1; off < 64; off <<= 1) {
      mx = fmaxf(mx, __shfl_xor(mx, off, 64));
      sm += __shfl_xor(sm, off, 64);
    }
    if (lane == 0) {
      z[b * 2048 + o] = mx;
      z[b * 2048 + 1024 + o] = sm * (1.f / 1024.f);
    }
  }
}

// ---------------------------------------------------------------------------
// fallback f32 conv1d (used only if ws too small for MFMA buffers)
// ---------------------------------------------------------------------------
__global__ void bn_finalize_kernel(float* __restrict__ stats,
                                   const float* __restrict__ g,
                                   const float* __restrict__ bb, int cout,
                                   float inv_cnt) {
  const int o = blockIdx.x * 256 + threadIdx.x;
  if (o >= cout) return;
  const float mean = stats[o] * inv_cnt;
  const float var = stats[1024 + o] * inv_cnt - mean * mean;
  const float s = g[o] * rsqrtf(var + BNEPS);
  stats[2048 + o] = s;
  stats[3072 + o] = bb[o] - mean * s;
}

__global__ __launch_bounds__(256) void conv1d_gemm_kernel(
    const float* __restrict__ hcat, const float* __restrict__ WT5,
    float* __restrict__ stats, float* __restrict__ Y5) {
  __shared__ __align__(16) float s_w[8][64];
  __shared__ __align__(16) float s_h[8][64];
  __shared__ __align__(16) float s_red[64][16];
  const int t = threadIdx.x;
  const int bx = blockIdx.x;
  const int b = bx >> 8;
  const int o0 = ((bx >> 4) & 15) * 64;
  const int n0 = (bx & 15) * 64;
  const float* hb = hcat + (size_t)b * (512 * 1024);
  const int to = (t >> 4) * 4;
  const int tn = (t & 15) * 4;
  float acc[4][4] = {};
  for (int c0 = 0; c0 < 512; c0 += 8) {
    for (int i = t; i < 8 * 64; i += 256) {
      const int cc = i >> 6, col = i & 63;
      s_w[cc][col] = WT5[(c0 + cc) * 1024 + o0 + col];
      s_h[cc][col] = hb[(c0 + cc) * NN + n0 + col];
    }
    __syncthreads();
#pragma unroll
    for (int cc = 0; cc < 8; ++cc) {
      const float4 wv = *(const float4*)&s_w[cc][to];
      const float4 hv = *(const float4*)&s_h[cc][tn];
      const float wa[4] = {wv.x, wv.y, wv.z, wv.w};
      const float ha[4] = {hv.x, hv.y, hv.z, hv.w};
#pragma unroll
      for (int i = 0; i < 4; ++i)
#pragma unroll
        for (int j = 0; j < 4; ++j) acc[i][j] = fmaf(wa[i], ha[j], acc[i][j]);
    }
    __syncthreads();
  }
#pragma unroll
  for (int i = 0; i < 4; ++i) {
    *(float4*)&Y5[((size_t)(b << 10) + o0 + to + i) * NN + n0 + tn] =
        make_float4(acc[i][0], acc[i][1], acc[i][2], acc[i][3]);
  }
#pragma unroll
  for (int i = 0; i < 4; ++i)
    s_red[to + i][t & 15] = acc[i][0] + acc[i][1] + acc[i][2] + acc[i][3];
  __syncthreads();
  if (t < 64) {
    float s = 0.f;
#pragma unroll
    for (int g2 = 0; g2 < 16; ++g2) s += s_red[t][g2];
    atomicAdd(&stats[o0 + t], s);
  }
  __syncthreads();
#pragma unroll
  for (int i = 0; i < 4; ++i) {
    float s = 0.f;
#pragma unroll
    for (int j = 0; j < 4; ++j) s = fmaf(acc[i][j], acc[i][j], s);
    s_red[to + i][t & 15] = s;
  }
  __syncthreads();
  if (t < 64) {
    float s = 0.f;
#pragma unroll
    for (int g2 = 0; g2 < 16; ++g2) s += s_red[t][g2];
    atomicAdd(&stats[1024 + o0 + t], s);
  }
}

__global__ __launch_bounds__(256) void pool_kernel(
    const float* __restrict__ Y5, const float* __restrict__ stats,
    float* __restrict__ z) {
  const int t = threadIdx.x;
  const int lane = t & 63;
  const int bx = blockIdx.x;
  const int b = bx >> 8;
  const int o = (bx & 255) * 4 + (t >> 6);
  const float sc = stats[2048 + o], sh = stats[3072 + o];
  const float* yr = Y5 + ((size_t)(b << 10) + o) * NN;
  float mx = -3.4e38f, sm = 0.f;
#pragma unroll
  for (int j = 0; j < 16; ++j) {
    const float y = lrelu(fmaf(sc, yr[j * 64 + lane], sh));
    mx = fmaxf(mx, y);
    sm += y;
  }
  for (int off = 32; off > 0; off >>= 1) {
    mx = fmaxf(mx, __shfl_down(mx, off, 64));
    sm += __shfl_down(sm, off, 64);
  }
  if (lane == 0) {
    z[b * 2048 + o] = mx;
    z[b * 2048 + 1024 + o] = sm * (1.f / 1024.f);
  }
}

// ---------------------------------------------------------------------------
// MLP layer with batch-of-8 BN + lrelu fused. W/bias read RAW from inputs.
// ---------------------------------------------------------------------------
__global__ __launch_bounds__(256) void mlp_kernel(
    const float* __restrict__ zin, const void* __restrict__ W,
    const void* __restrict__ bias, const int* __restrict__ flags, int wfl,
    int bfl, const float* __restrict__ g, const float* __restrict__ bb,
    int kin, float* __restrict__ out, int O) {
  __shared__ float s_red[256];
  __shared__ float s_y[8];
  const int t = threadIdx.x;
  const int o = blockIdx.x;
  const int fw = flags[wfl];
  float acc[8];
#pragma unroll
  for (int b = 0; b < 8; ++b) acc[b] = 0.f;
  for (int c = t; c < kin; c += 256) {
    const float w = load_in(W, fw, o * kin + c);
#pragma unroll
    for (int b = 0; b < 8; ++b) acc[b] = fmaf(w, zin[b * kin + c], acc[b]);
  }
  for (int b = 0; b < 8; ++b) {
    s_red[t] = acc[b];
    __syncthreads();
    for (int s = 128; s > 0; s >>= 1) {
      if (t < s) s_red[t] += s_red[t + s];
      __syncthreads();
    }
    if (t == 0)
      s_y[b] = s_red[0] + (bias ? load_in(bias, flags[bfl], o) : 0.f);
    __syncthreads();
  }
  if (t == 0) {
    float m = 0.f;
    for (int b = 0; b < 8; ++b) m += s_y[b];
    m *= 0.125f;
    float v = 0.f;
    for (int b = 0; b < 8; ++b) { const float d = s_y[b] - m; v = fmaf(d, d, v); }
    v *= 0.125f;
    const float s = g[o] * rsqrtf(v + BNEPS);
    const float sh = bb[o] - m * s;
    for (int b = 0; b < 8; ++b) out[b * O + o] = lrelu(fmaf(s, s_y[b], sh));
  }
}

// final: out = z2 @ Wl3^T + bl3 (raw reads); output dtype from flags.
__global__ void final_kernel(const float* __restrict__ z2,
                             const void* __restrict__ Wl3,
                             const void* __restrict__ bl3,
                             const int* __restrict__ flags, void* out) {
  const int j = blockIdx.x * 256 + threadIdx.x;
  if (j >= 320) return;
  int anyf32 = 0, anybf = 0;
  for (int i = 0; i < NIN; ++i) {
    const int fl = flags[i];
    if (fl == 0) anyf32 = 1;
    if (fl == 1) anybf = 1;
  }
  const int bf16out = (anybf && !anyf32) ? 1 : 0;
  const int fw = flags[9], fb = flags[10];
  const int b = j / 40, o = j - b * 40;
  float s = load_in(bl3, fb, o);
  for (int c = 0; c < 256; ++c)
    s = fmaf(z2[b * 256 + c], load_in(Wl3, fw, o * 256 + c), s);
  if (bf16out) ((__hip_bfloat16*)out)[j] = __float2bfloat16(s);
  else ((float*)out)[j] = s;
}

// ---------------------------------------------------------------------------
template <int C, int O>
static void run_stage(float* wsf, const float* xbase, int bstr, int widx,
                      int gidx, int bidx, int stat, float* hout,
                      unsigned short* hp, int coff, hipStream_t stream) {
  int* idxb = reinterpret_cast<int*>(wsf + IDXo);
  float* U = wsf + U_OFF;
  float* Vd = wsf + VD_OFF;
  float* ysel = wsf + YS_OFF;
  float* stats = wsf + STATSo + stat * 4096;
  tg_kernel<C, O><<<512 + BB * 16 * (O / 64), 512, 0, stream>>>(
      xbase, bstr, wsf + widx, U, Vd, idxb);
  edge_pass_kernel<O><<<512, 256, 0, stream>>>(U, Vd, idxb, wsf + gidx, stats,
                                               ysel);
  bn_apply_kernel<O><<<BB * 32 * (O / 32), 256, 0, stream>>>(
      ysel, stats, wsf + gidx, wsf + bidx, hout, hp, coff);
}

extern "C" void kernel_launch(void* const* d_in, const int* in_sizes, int n_in,
                              void* d_out, int out_size, void* d_ws,
                              size_t ws_size, hipStream_t stream) {
  (void)in_sizes; (void)n_in; (void)out_size;
  float* wsf = reinterpret_cast<float*>(d_ws);
  int* flags = reinterpret_cast<int*>(wsf + FLAGSo);
  float* hcat = wsf + HCATo;
  const bool mf = ws_size >= WS_NEED_MFMA;
  unsigned short* hp = mf ? reinterpret_cast<unsigned short*>(wsf + HBFo) : nullptr;
  unsigned short* w5p = reinterpret_cast<unsigned short*>(wsf + W5BFo);

  Ptrs ptrs;
  for (int i = 0; i < NIN; ++i) ptrs.p[i] = d_in[i];

  detect_kernel<<<NIN, 64, 0, stream>>>(ptrs, flags);
  const int nmain = mf ? NMAIN_MF : NCONV;
  convert_kernel<<<nmain + 80 + 256, 256, 0, stream>>>(ptrs, flags, wsf,
                                                       mf ? 1 : 0, nmain);

  run_stage<3, 64>(wsf, wsf + XIN, 3 * NN, WT1, G1, B1o, 0, hcat, hp, 0,
                   stream);
  run_stage<64, 64>(wsf, hcat, 512 * NN, WT2, G2, B2o, 1, hcat + 64 * NN, hp,
                    64, stream);
  run_stage<64, 128>(wsf, hcat + 64 * NN, 512 * NN, WT3, G3, B3o, 2,
                     hcat + 128 * NN, hp, 128, stream);
  // stage 4: f32 hout is dead in the MFMA path (only packed hp consumed)
  run_stage<128, 256>(wsf, hcat + 128 * NN, 512 * NN, WT4, G4, B4o, 3,
                      mf ? nullptr : (hcat + 256 * NN), hp, 256, stream);

  // conv1d 512->1024 + BN + pool
  float* Y5 = wsf + Y5_OFF;
  float* st5 = wsf + STATSo + 4 * 4096;
  if (mf) {
    conv1d_mfma_kernel<<<512, 256, 0, stream>>>(hp, w5p, Y5);
    c1pool_kernel<<<1024, 256, 0, stream>>>(Y5, wsf + G5, wsf + B5o,
                                            wsf + Z2048o);
  } else {
    conv1d_gemm_kernel<<<2048, 256, 0, stream>>>(hcat, wsf + WT5, st5, Y5);
    bn_finalize_kernel<<<4, 256, 0, stream>>>(st5, wsf + G5, wsf + B5o, 1024,
                                              1.f / 8192.f);
    pool_kernel<<<BB * 256, 256, 0, stream>>>(Y5, st5, wsf + Z2048o);
  }

  // MLP head (raw W/bias reads)
  mlp_kernel<<<512, 256, 0, stream>>>(wsf + Z2048o, d_in[6], nullptr, flags,
      6, 0, wsf + G6, wsf + B6o, 2048, wsf + Z1o, 512);
  mlp_kernel<<<256, 256, 0, stream>>>(wsf + Z1o, d_in[7], d_in[8], flags,
      7, 8, wsf + G7, wsf + B7o, 512, wsf + Z2o, 256);
  final_kernel<<<2, 256, 0, stream>>>(wsf + Z2o, d_in[9], d_in[10],
      flags, d_out);
}